// Round 4
// baseline (334.501 us; speedup 1.0000x reference)
//
#include <hip/hip_runtime.h>
#include <hip/hip_bf16.h>

#define BQ 4
#define LQ 4096
#define DM 512
#define DK 64
#define NROWS (BQ * DK)        // 256
#define TOPK 16

// async global->LDS, 16B per lane; LDS dest is wave-uniform base + lane*16B.
__device__ __forceinline__ void gl_lds16(const float* g, float* s) {
  auto g1 = (const __attribute__((address_space(1))) float*)(uintptr_t)g;
  auto s3 = (__attribute__((address_space(3))) float*)(uint32_t)(uintptr_t)s;
  __builtin_amdgcn_global_load_lds(g1, s3, 16, 0, 0);
}

// ---------------------------------------------------------------------------
// Projection body: out[b*64+j][i] = sum_k x[b*4096+i][k]*Wq[k][j] + bq[j]
// 64x64 block tile, BK=64, 4x4 thread tile. DUP=1 writes a second copy at
// +4096 within rows of length ldo (=8192) for circular-window reads.
// ---------------------------------------------------------------------------
template <int DUP>
__device__ __forceinline__ void proj_body(const float* __restrict__ x,
                                          float* __restrict__ out, int ldo,
                                          const float* __restrict__ Wq,
                                          const float* __restrict__ bq) {
  __shared__ __align__(16) float smem[8192];   // 32 KB: xs[4096] | wl[4096]
  float* xs = smem;
  float* wl = smem + 4096;

  const int tid = threadIdx.x;
  const int lane = tid & 63, wvi = tid >> 6;
  const int tx = tid & 15, ty = tid >> 4;
  const int R0 = blockIdx.x * 64;

  float acc[4][4];
#pragma unroll
  for (int r = 0; r < 4; ++r)
#pragma unroll
    for (int c = 0; c < 4; ++c) acc[r][c] = 0.f;

  const int qg = lane & 15, r4 = lane >> 4;
  const int colw = tid & 63, kseg = tid >> 6;

  for (int kc = 0; kc < DM; kc += 64) {
#pragma unroll
    for (int is = 0; is < 4; ++is) {
      int row = wvi * 16 + is * 4 + r4;
      gl_lds16(&x[(size_t)(R0 + row) * DM + kc + qg * 4],
               &xs[(wvi * 16 + is * 4) * 64]);
    }
    float wv16[16];
#pragma unroll
    for (int u = 0; u < 16; ++u)
      wv16[u] = Wq[(size_t)(kc + kseg * 16 + u) * DK + colw];
#pragma unroll
    for (int kk4 = 0; kk4 < 4; ++kk4) {
      int phys = ((kseg * 4 + kk4) ^ (colw & 7)) << 2;
      float4 o;
      o.x = wv16[kk4 * 4]; o.y = wv16[kk4 * 4 + 1];
      o.z = wv16[kk4 * 4 + 2]; o.w = wv16[kk4 * 4 + 3];
      *reinterpret_cast<float4*>(&wl[colw * 64 + phys]) = o;
    }
    __syncthreads();

    const int c0 = tx * 4, s0 = c0 & 7, s1 = (c0 + 1) & 7,
              s2 = (c0 + 2) & 7, s3 = (c0 + 3) & 7;
#pragma unroll
    for (int kq = 0; kq < 16; ++kq) {
      const int kqe = kq ^ tx;
      float4 xv[4], wv[4];
#pragma unroll
      for (int rr = 0; rr < 4; ++rr)
        xv[rr] = *reinterpret_cast<const float4*>(
            &xs[(ty * 4 + rr) * 64 + (kqe << 2)]);
      wv[0] = *reinterpret_cast<const float4*>(&wl[(c0 + 0) * 64 + ((kqe ^ s0) << 2)]);
      wv[1] = *reinterpret_cast<const float4*>(&wl[(c0 + 1) * 64 + ((kqe ^ s1) << 2)]);
      wv[2] = *reinterpret_cast<const float4*>(&wl[(c0 + 2) * 64 + ((kqe ^ s2) << 2)]);
      wv[3] = *reinterpret_cast<const float4*>(&wl[(c0 + 3) * 64 + ((kqe ^ s3) << 2)]);
#pragma unroll
      for (int rr = 0; rr < 4; ++rr)
#pragma unroll
        for (int cc = 0; cc < 4; ++cc) {
          acc[rr][cc] = fmaf(xv[rr].x, wv[cc].x, acc[rr][cc]);
          acc[rr][cc] = fmaf(xv[rr].y, wv[cc].y, acc[rr][cc]);
          acc[rr][cc] = fmaf(xv[rr].z, wv[cc].z, acc[rr][cc]);
          acc[rr][cc] = fmaf(xv[rr].w, wv[cc].w, acc[rr][cc]);
        }
    }
    __syncthreads();
  }

  // epilogue: bias + transpose through LDS, coalesced store.
  float* tr = smem;  // [64][65]
  float bb[4];
#pragma unroll
  for (int cc = 0; cc < 4; ++cc) bb[cc] = bq[tx * 4 + cc];
#pragma unroll
  for (int rr = 0; rr < 4; ++rr)
#pragma unroll
    for (int cc = 0; cc < 4; ++cc)
      tr[(tx * 4 + cc) * 65 + ty * 4 + rr] = acc[rr][cc] + bb[cc];
  __syncthreads();
  const int b = R0 >> 12, i0 = R0 & (LQ - 1);
#pragma unroll
  for (int v = 0; v < 16; ++v) {
    int f = v * 256 + tid;
    int j = f >> 6, i = f & 63;
    float val = tr[j * 65 + i];
    size_t base = ((size_t)b * DK + j) * ldo + i0 + i;
    out[base] = val;
    if (DUP) out[base + LQ] = val;
  }
}

__global__ __launch_bounds__(256) void projqk_kernel(
    const float* __restrict__ q_in, const float* __restrict__ k_in,
    const float* __restrict__ Wq, const float* __restrict__ bq,
    float* __restrict__ qd, float* __restrict__ kp) {
  if (blockIdx.z == 0) proj_body<1>(q_in, qd, 2 * LQ, Wq, bq);
  else                 proj_body<0>(k_in, kp, LQ, Wq, bq);
}

__global__ __launch_bounds__(256) void projv_kernel(
    const float* __restrict__ v_in, const float* __restrict__ Wq,
    const float* __restrict__ bq, float* __restrict__ vp) {
  proj_body<0>(v_in, vp, LQ, Wq, bq);
}

// ---------------------------------------------------------------------------
// Kernel 2 v3: direct circular correlation, ZERO LDS.
// corrP[part][row][tau] = sum_{t in part} k[t] * q[t+tau]
// q windows from duplicated qd[row][8192] via global float4 (L1-resident row);
// k via wave-uniform loads (SMEM path). grid (4, 256), block 256,
// thread = 16 consecutive taus, 32-float sliding window in registers.
// ---------------------------------------------------------------------------
__global__ __launch_bounds__(256) void corr_kernel(
    const float* __restrict__ qd, const float* __restrict__ kp,
    float* __restrict__ corrP) {
  const int part = blockIdx.x;   // 0..3
  const int row = blockIdx.y;    // 0..255
  const int tid = threadIdx.x;
  const int t0 = part * 1024;
  const int tau0 = tid * 16;

  const float* qb = qd + ((size_t)row << 13) + t0 + tau0;  // window base
  const float* kr = kp + ((size_t)row << 12) + t0;         // uniform

  float acc[16];
#pragma unroll
  for (int j = 0; j < 16; ++j) acc[j] = 0.f;

  for (int tt = 0; tt < 1024; tt += 16) {
    float kt[16];
#pragma unroll
    for (int c = 0; c < 4; ++c) {
      float4 kv = *reinterpret_cast<const float4*>(kr + tt + c * 4);
      kt[c * 4] = kv.x; kt[c * 4 + 1] = kv.y;
      kt[c * 4 + 2] = kv.z; kt[c * 4 + 3] = kv.w;
    }
    float qw[32];
#pragma unroll
    for (int c = 0; c < 8; ++c) {
      float4 qv = *reinterpret_cast<const float4*>(qb + tt + c * 4);
      qw[c * 4] = qv.x; qw[c * 4 + 1] = qv.y;
      qw[c * 4 + 2] = qv.z; qw[c * 4 + 3] = qv.w;
    }
#pragma unroll
    for (int i = 0; i < 16; ++i)
#pragma unroll
      for (int j = 0; j < 16; ++j)
        acc[j] = fmaf(kt[i], qw[i + j], acc[j]);
  }

  float* cp = corrP + ((size_t)part * NROWS + row) * LQ + tau0;
#pragma unroll
  for (int j4 = 0; j4 < 16; j4 += 4) {
    float4 o; o.x = acc[j4]; o.y = acc[j4 + 1]; o.z = acc[j4 + 2]; o.w = acc[j4 + 3];
    *reinterpret_cast<float4*>(&cp[j4]) = o;
  }
}

// ---------------------------------------------------------------------------
// Kernel 3: top-16 (jax tie-break: smaller index on equal) + softmax
// ---------------------------------------------------------------------------
__global__ void topk_kernel(const float* __restrict__ corrP,
                            int* __restrict__ lagB,
                            float* __restrict__ wtB) {
  const int row = blockIdx.x, tid = threadIdx.x;
  const float* c0 = corrP + (size_t)row * LQ;
  const size_t PS = (size_t)NROWS * LQ;

  float v[16]; int ix[16];
#pragma unroll
  for (int m = 0; m < 16; ++m) {
    int tau = m * 256 + tid;
    float s = c0[tau] + c0[PS + tau] + c0[2 * PS + tau] + c0[3 * PS + tau];
    v[m] = fabsf(s);
    ix[m] = tau;
  }

  __shared__ float rv[4]; __shared__ int ri[4];
  __shared__ float sval[TOPK]; __shared__ int sidx[TOPK];
  const int lane = tid & 63, wid = tid >> 6;

  for (int round = 0; round < TOPK; ++round) {
    float bv = -1.f; int bi = 0x7fffffff;
#pragma unroll
    for (int m = 0; m < 16; ++m)
      if (v[m] > bv || (v[m] == bv && ix[m] < bi)) { bv = v[m]; bi = ix[m]; }
#pragma unroll
    for (int off = 32; off > 0; off >>= 1) {
      float ov = __shfl_down(bv, off);
      int oi = __shfl_down(bi, off);
      if (ov > bv || (ov == bv && oi < bi)) { bv = ov; bi = oi; }
    }
    if (lane == 0) { rv[wid] = bv; ri[wid] = bi; }
    __syncthreads();
    if (tid == 0) {
      float fv = rv[0]; int fi = ri[0];
      for (int w = 1; w < 4; ++w)
        if (rv[w] > fv || (rv[w] == fv && ri[w] < fi)) { fv = rv[w]; fi = ri[w]; }
      sval[round] = fv; sidx[round] = fi;
    }
    __syncthreads();
    int widx = sidx[round];
#pragma unroll
    for (int m = 0; m < 16; ++m)
      if (ix[m] == widx) v[m] = -1.f;
  }

  if (tid == 0) {
    float m0 = sval[0], s = 0.f, e[TOPK];
    for (int k = 0; k < TOPK; ++k) { e[k] = expf(sval[k] - m0); s += e[k]; }
    float inv = 1.f / s;
    for (int k = 0; k < TOPK; ++k) {
      wtB[row * TOPK + k] = e[k] * inv;
      lagB[row * TOPK + k] = sidx[k];
    }
  }
}

// ---------------------------------------------------------------------------
// Kernel 4: aggregation  aggT[row][t] = sum_k w_k * v[row][(t+lag_k)%L]
// ---------------------------------------------------------------------------
__global__ void agg_kernel(const float* __restrict__ vpT,
                           const int* __restrict__ lagB,
                           const float* __restrict__ wtB,
                           float* __restrict__ aggT) {
  const int row = blockIdx.x, tid = threadIdx.x;
  __shared__ __align__(16) float vr[2 * LQ];
  __shared__ float w[TOPK]; __shared__ int lg[TOPK];

  const float* v0 = vpT + (size_t)row * LQ;
  for (int x = tid; x < LQ; x += 256) {
    float val = v0[x];
    vr[x] = val; vr[x + LQ] = val;
  }
  if (tid < TOPK) { w[tid] = wtB[row * TOPK + tid]; lg[tid] = lagB[row * TOPK + tid]; }
  __syncthreads();

  float wr[TOPK]; int lr[TOPK];
#pragma unroll
  for (int k = 0; k < TOPK; ++k) { wr[k] = w[k]; lr[k] = lg[k]; }

  for (int m = 0; m < 16; ++m) {
    int t = m * 256 + tid;
    float a = 0.f;
#pragma unroll
    for (int k = 0; k < TOPK; ++k) a = fmaf(wr[k], vr[t + lr[k]], a);
    aggT[(size_t)row * LQ + t] = a;
  }
}

// ---------------------------------------------------------------------------
// Kernel 5: transpose + head-broadcast  out[b][t][c] = aggT[b][c&63][t]
// ---------------------------------------------------------------------------
__global__ void trans_kernel(const float* __restrict__ aggT,
                             float* __restrict__ out) {
  const int b = blockIdx.y;
  const int t0 = blockIdx.x * 64;
  const int tid = threadIdx.x;
  __shared__ float ts[64][65];

#pragma unroll
  for (int v = 0; v < 16; ++v) {
    int f = v * 256 + tid;
    int d = f >> 6, tt = f & 63;
    ts[d][tt] = aggT[((size_t)b * DK + d) * LQ + t0 + tt];
  }
  __syncthreads();

#pragma unroll
  for (int v = 0; v < 128; ++v) {
    int f = v * 256 + tid;
    int tt = f >> 9, c = f & 511;
    out[((size_t)b * LQ + t0 + tt) * (8 * DK) + c] = ts[c & 63][tt];
  }
}

// ---------------------------------------------------------------------------
// ws layout (floats), peak 7M = 28 MB (proven footprint):
//   [0, 2M)   qd [256][8192] q duplicated   -> after topk: lagB/wtB (8K)
//   [2M, 3M)  kp [256][4096]                -> after corr: vp (projv)
//   [3M, 7M)  corrP [4][256][4096]          -> after topk: aggT (1M)
// ---------------------------------------------------------------------------
extern "C" void kernel_launch(void* const* d_in, const int* in_sizes, int n_in,
                              void* d_out, int out_size, void* d_ws, size_t ws_size,
                              hipStream_t stream) {
  const float* q_in = (const float*)d_in[0];
  const float* k_in = (const float*)d_in[1];
  const float* v_in = (const float*)d_in[2];
  const float* Wq   = (const float*)d_in[3];
  const float* bq   = (const float*)d_in[4];
  float* out = (float*)d_out;
  float* ws  = (float*)d_ws;

  const size_t M = (size_t)NROWS * LQ;        // 1,048,576 floats
  float* qd    = ws;                          // [0, 2M)
  float* kp    = ws + 2 * M;                  // [2M, 3M)
  float* corrP = ws + 3 * M;                  // [3M, 7M)
  int*   lagB  = (int*)ws;                    // reuse qd (dead after corr)
  float* wtB   = ws + NROWS * TOPK;
  float* vp    = kp;                          // reuse kp (dead after corr)
  float* aggT  = corrP;                       // reuse corrP part0 (dead after topk)

  projqk_kernel<<<dim3(256, 1, 2), 256, 0, stream>>>(q_in, k_in, Wq, bq, qd, kp);
  corr_kernel<<<dim3(4, NROWS), 256, 0, stream>>>(qd, kp, corrP);
  topk_kernel<<<NROWS, 256, 0, stream>>>(corrP, lagB, wtB);
  projv_kernel<<<dim3(256, 1, 1), 256, 0, stream>>>(v_in, Wq, bq, vp);
  agg_kernel<<<NROWS, 256, 0, stream>>>(vp, lagB, wtB, aggT);
  trans_kernel<<<dim3(LQ / 64, BQ), 256, 0, stream>>>(aggT, out);
}

// Round 5
// 259.990 us; speedup vs baseline: 1.2866x; 1.2866x over previous
//
#include <hip/hip_runtime.h>
#include <hip/hip_bf16.h>

#define BQ 4
#define LQ 4096
#define DM 512
#define DK 64
#define NROWS (BQ * DK)        // 256
#define TOPK 16

// async global->LDS, 16B per lane; LDS dest is wave-uniform base + lane*16B,
// global source is PER-LANE (so swizzled layouts = pre-swizzled source).
__device__ __forceinline__ void gl_lds16(const float* g, float* s) {
  auto g1 = (const __attribute__((address_space(1))) float*)(uintptr_t)g;
  auto s3 = (__attribute__((address_space(3))) float*)(uint32_t)(uintptr_t)s;
  __builtin_amdgcn_global_load_lds(g1, s3, 16, 0, 0);
}

// Quad swizzle folding BOTH bit-3 and bit-6 groups into the bank group:
// safe for phase groupings {8 consecutive lanes} AND {l,l+16,l+32,l+48}.
// Involution (only low 3 bits change, mask from unchanged higher bits).
__device__ __forceinline__ int swzq(int g) {
  return g ^ ((g >> 3) & 7) ^ ((g >> 6) & 7);
}

// ---------------------------------------------------------------------------
// Projection body: out[b*64+j][i] = sum_k x[b*4096+i][k]*Wq[k][j] + bq[j]
// 64x64 block tile, BK=64, 4x4 thread tile. xs staged with row-XOR column
// permutation (pre-swizzled global source) so reads are >=2-way worst case.
// ---------------------------------------------------------------------------
template <int DUP>
__device__ __forceinline__ void proj_body(const float* __restrict__ x,
                                          float* __restrict__ out, int ldo,
                                          const float* __restrict__ Wq,
                                          const float* __restrict__ bq) {
  __shared__ __align__(16) float smem[8192];   // 32 KB: xs[4096] | wl[4096]
  float* xs = smem;
  float* wl = smem + 4096;

  const int tid = threadIdx.x;
  const int lane = tid & 63, wvi = tid >> 6;
  const int tx = tid & 15, ty = tid >> 4;
  const int R0 = blockIdx.x * 64;

  float acc[4][4];
#pragma unroll
  for (int r = 0; r < 4; ++r)
#pragma unroll
    for (int c = 0; c < 4; ++c) acc[r][c] = 0.f;

  const int qg = lane & 15, r4 = lane >> 4;
  const int colw = tid & 63, kseg = tid >> 6;

  for (int kc = 0; kc < DM; kc += 64) {
    // xs: wave wvi stages rows [wvi*16,+16); lane sources column (qg^(row&7)).
#pragma unroll
    for (int is = 0; is < 4; ++is) {
      int rloc = wvi * 16 + is * 4 + r4;
      gl_lds16(&x[(size_t)(R0 + rloc) * DM + kc + ((qg ^ (rloc & 7)) << 2)],
               &xs[(wvi * 16 + is * 4) * 64]);
    }
    float wv16[16];
#pragma unroll
    for (int u = 0; u < 16; ++u)
      wv16[u] = Wq[(size_t)(kc + kseg * 16 + u) * DK + colw];
#pragma unroll
    for (int kk4 = 0; kk4 < 4; ++kk4) {
      int phys = ((kseg * 4 + kk4) ^ (colw & 7)) << 2;
      float4 o;
      o.x = wv16[kk4 * 4]; o.y = wv16[kk4 * 4 + 1];
      o.z = wv16[kk4 * 4 + 2]; o.w = wv16[kk4 * 4 + 3];
      *reinterpret_cast<float4*>(&wl[colw * 64 + phys]) = o;
    }
    __syncthreads();

    const int c0 = tx * 4, s0 = c0 & 7, s1 = (c0 + 1) & 7,
              s2 = (c0 + 2) & 7, s3 = (c0 + 3) & 7;
#pragma unroll
    for (int kq = 0; kq < 16; ++kq) {
      const int kqe = kq ^ tx;
      float4 xv[4], wv[4];
#pragma unroll
      for (int rr = 0; rr < 4; ++rr) {
        int row = ty * 4 + rr;
        xv[rr] = *reinterpret_cast<const float4*>(
            &xs[row * 64 + ((kqe ^ (row & 7)) << 2)]);
      }
      wv[0] = *reinterpret_cast<const float4*>(&wl[(c0 + 0) * 64 + ((kqe ^ s0) << 2)]);
      wv[1] = *reinterpret_cast<const float4*>(&wl[(c0 + 1) * 64 + ((kqe ^ s1) << 2)]);
      wv[2] = *reinterpret_cast<const float4*>(&wl[(c0 + 2) * 64 + ((kqe ^ s2) << 2)]);
      wv[3] = *reinterpret_cast<const float4*>(&wl[(c0 + 3) * 64 + ((kqe ^ s3) << 2)]);
#pragma unroll
      for (int rr = 0; rr < 4; ++rr)
#pragma unroll
        for (int cc = 0; cc < 4; ++cc) {
          acc[rr][cc] = fmaf(xv[rr].x, wv[cc].x, acc[rr][cc]);
          acc[rr][cc] = fmaf(xv[rr].y, wv[cc].y, acc[rr][cc]);
          acc[rr][cc] = fmaf(xv[rr].z, wv[cc].z, acc[rr][cc]);
          acc[rr][cc] = fmaf(xv[rr].w, wv[cc].w, acc[rr][cc]);
        }
    }
    __syncthreads();
  }

  // epilogue: bias + transpose through LDS, coalesced store.
  float* tr = smem;  // [64][65]
  float bb[4];
#pragma unroll
  for (int cc = 0; cc < 4; ++cc) bb[cc] = bq[tx * 4 + cc];
#pragma unroll
  for (int rr = 0; rr < 4; ++rr)
#pragma unroll
    for (int cc = 0; cc < 4; ++cc)
      tr[(tx * 4 + cc) * 65 + ty * 4 + rr] = acc[rr][cc] + bb[cc];
  __syncthreads();
  const int b = R0 >> 12, i0 = R0 & (LQ - 1);
#pragma unroll
  for (int v = 0; v < 16; ++v) {
    int f = v * 256 + tid;
    int j = f >> 6, i = f & 63;
    float val = tr[j * 65 + i];
    size_t base = ((size_t)b * DK + j) * ldo + i0 + i;
    out[base] = val;
    if (DUP) out[base + LQ] = val;
  }
}

__global__ __launch_bounds__(256) void projqk_kernel(
    const float* __restrict__ q_in, const float* __restrict__ k_in,
    const float* __restrict__ Wq, const float* __restrict__ bq,
    float* __restrict__ qd, float* __restrict__ kp) {
  if (blockIdx.z == 0) proj_body<1>(q_in, qd, 2 * LQ, Wq, bq);
  else                 proj_body<0>(k_in, kp, LQ, Wq, bq);
}

__global__ __launch_bounds__(256) void projv_kernel(
    const float* __restrict__ v_in, const float* __restrict__ Wq,
    const float* __restrict__ bq, float* __restrict__ vp) {
  proj_body<0>(v_in, vp, LQ, Wq, bq);
}

// ---------------------------------------------------------------------------
// Kernel 2 v4: LDS correlation, J=32 taus/thread, t split across 2 halves.
// corrP[part][row][tau] = sum_{t in [1024p,1024p+1024)} k[t]*q[t+tau]
// grid (4,256), block 256 (th = tid>>7 picks t-half; j = tid&127 -> 32 taus).
// qs staged via gl_lds16 with involution-swizzled global source; reads use
// swzq -> conflict-free under both phase-group hypotheses. End: LDS reduce.
// ---------------------------------------------------------------------------
__global__ __launch_bounds__(256, 4) void corr_kernel(
    const float* __restrict__ qd, const float* __restrict__ kp,
    float* __restrict__ corrP) {
  const int part = blockIdx.x;   // 0..3
  const int row = blockIdx.y;    // 0..255
  const int tid = threadIdx.x;
  const int j = tid & 127;       // tau group: taus [32j, 32j+32)
  const int th = tid >> 7;       // t half
  const int lane = tid & 63, wv = tid >> 6;

  __shared__ __align__(16) float qs[5120];   // 20 KB (1280 quads)
  __shared__ __align__(16) float ks[1024];   // 4 KB

  const float* qr = qd + ((size_t)row << 13) + part * 1024;  // duplicated row
  const float* kr = kp + ((size_t)row << 12) + part * 1024;

  // stage qs: LDS quad g holds global quad swzq(g) (involution).
#pragma unroll
  for (int it = 0; it < 5; ++it) {
    int Q0 = it * 256 + wv * 64;
    gl_lds16(qr + (swzq(Q0 + lane) << 2), &qs[Q0 << 2]);
  }
  gl_lds16(kr + ((wv * 64 + lane) << 2), &ks[wv << 8]);  // linear
  __syncthreads();

  const int tau0 = j * 32;
  float acc[32];
#pragma unroll
  for (int n = 0; n < 32; ++n) acc[n] = 0.f;

  const int tl0 = th * 512;
  for (int tl = tl0; tl < tl0 + 512; tl += 16) {
    float kt[16];
#pragma unroll
    for (int c = 0; c < 4; ++c) {
      float4 kv = *reinterpret_cast<const float4*>(&ks[tl + c * 4]);
      kt[c * 4] = kv.x; kt[c * 4 + 1] = kv.y;
      kt[c * 4 + 2] = kv.z; kt[c * 4 + 3] = kv.w;
    }
    float qw[48];
    const int gq = j * 8 + (tl >> 2);
#pragma unroll
    for (int u = 0; u < 12; ++u) {
      float4 qv = *reinterpret_cast<const float4*>(&qs[swzq(gq + u) << 2]);
      qw[u * 4] = qv.x; qw[u * 4 + 1] = qv.y;
      qw[u * 4 + 2] = qv.z; qw[u * 4 + 3] = qv.w;
    }
#pragma unroll
    for (int i = 0; i < 16; ++i)
#pragma unroll
      for (int n = 0; n < 32; ++n)
        acc[n] = fmaf(kt[i], qw[i + n], acc[n]);
  }

  // cross-half reduction through LDS (reuse qs; stride 36 breaks conflicts).
  __syncthreads();
  float* red = qs;
  if (th == 1) {
#pragma unroll
    for (int n4 = 0; n4 < 32; n4 += 4) {
      float4 o; o.x = acc[n4]; o.y = acc[n4 + 1];
      o.z = acc[n4 + 2]; o.w = acc[n4 + 3];
      *reinterpret_cast<float4*>(&red[j * 36 + n4]) = o;
    }
  }
  __syncthreads();
  if (th == 0) {
    float* cp = corrP + ((size_t)part * NROWS + row) * LQ + tau0;
#pragma unroll
    for (int n4 = 0; n4 < 32; n4 += 4) {
      float4 r = *reinterpret_cast<const float4*>(&red[j * 36 + n4]);
      float4 o;
      o.x = acc[n4] + r.x; o.y = acc[n4 + 1] + r.y;
      o.z = acc[n4 + 2] + r.z; o.w = acc[n4 + 3] + r.w;
      *reinterpret_cast<float4*>(&cp[n4]) = o;
    }
  }
}

// ---------------------------------------------------------------------------
// Kernel 3: top-16 (jax tie-break: smaller index on equal) + softmax
// ---------------------------------------------------------------------------
__global__ void topk_kernel(const float* __restrict__ corrP,
                            int* __restrict__ lagB,
                            float* __restrict__ wtB) {
  const int row = blockIdx.x, tid = threadIdx.x;
  const float* c0 = corrP + (size_t)row * LQ;
  const size_t PS = (size_t)NROWS * LQ;

  float v[16]; int ix[16];
#pragma unroll
  for (int m = 0; m < 16; ++m) {
    int tau = m * 256 + tid;
    float s = c0[tau] + c0[PS + tau] + c0[2 * PS + tau] + c0[3 * PS + tau];
    v[m] = fabsf(s);
    ix[m] = tau;
  }

  __shared__ float rv[4]; __shared__ int ri[4];
  __shared__ float sval[TOPK]; __shared__ int sidx[TOPK];
  const int lane = tid & 63, wid = tid >> 6;

  for (int round = 0; round < TOPK; ++round) {
    float bv = -1.f; int bi = 0x7fffffff;
#pragma unroll
    for (int m = 0; m < 16; ++m)
      if (v[m] > bv || (v[m] == bv && ix[m] < bi)) { bv = v[m]; bi = ix[m]; }
#pragma unroll
    for (int off = 32; off > 0; off >>= 1) {
      float ov = __shfl_down(bv, off);
      int oi = __shfl_down(bi, off);
      if (ov > bv || (ov == bv && oi < bi)) { bv = ov; bi = oi; }
    }
    if (lane == 0) { rv[wid] = bv; ri[wid] = bi; }
    __syncthreads();
    if (tid == 0) {
      float fv = rv[0]; int fi = ri[0];
      for (int w = 1; w < 4; ++w)
        if (rv[w] > fv || (rv[w] == fv && ri[w] < fi)) { fv = rv[w]; fi = ri[w]; }
      sval[round] = fv; sidx[round] = fi;
    }
    __syncthreads();
    int widx = sidx[round];
#pragma unroll
    for (int m = 0; m < 16; ++m)
      if (ix[m] == widx) v[m] = -1.f;
  }

  if (tid == 0) {
    float m0 = sval[0], s = 0.f, e[TOPK];
    for (int k = 0; k < TOPK; ++k) { e[k] = expf(sval[k] - m0); s += e[k]; }
    float inv = 1.f / s;
    for (int k = 0; k < TOPK; ++k) {
      wtB[row * TOPK + k] = e[k] * inv;
      lagB[row * TOPK + k] = sidx[k];
    }
  }
}

// ---------------------------------------------------------------------------
// Kernel 4: aggregation  aggT[row][t] = sum_k w_k * v[row][(t+lag_k)%L]
// ---------------------------------------------------------------------------
__global__ void agg_kernel(const float* __restrict__ vpT,
                           const int* __restrict__ lagB,
                           const float* __restrict__ wtB,
                           float* __restrict__ aggT) {
  const int row = blockIdx.x, tid = threadIdx.x;
  __shared__ __align__(16) float vr[2 * LQ];
  __shared__ float w[TOPK]; __shared__ int lg[TOPK];

  const float* v0 = vpT + (size_t)row * LQ;
  for (int x = tid; x < LQ; x += 256) {
    float val = v0[x];
    vr[x] = val; vr[x + LQ] = val;
  }
  if (tid < TOPK) { w[tid] = wtB[row * TOPK + tid]; lg[tid] = lagB[row * TOPK + tid]; }
  __syncthreads();

  float wr[TOPK]; int lr[TOPK];
#pragma unroll
  for (int k = 0; k < TOPK; ++k) { wr[k] = w[k]; lr[k] = lg[k]; }

  for (int m = 0; m < 16; ++m) {
    int t = m * 256 + tid;
    float a = 0.f;
#pragma unroll
    for (int k = 0; k < TOPK; ++k) a = fmaf(wr[k], vr[t + lr[k]], a);
    aggT[(size_t)row * LQ + t] = a;
  }
}

// ---------------------------------------------------------------------------
// Kernel 5: transpose + head-broadcast  out[b][t][c] = aggT[b][c&63][t]
// ---------------------------------------------------------------------------
__global__ void trans_kernel(const float* __restrict__ aggT,
                             float* __restrict__ out) {
  const int b = blockIdx.y;
  const int t0 = blockIdx.x * 64;
  const int tid = threadIdx.x;
  __shared__ float ts[64][65];

#pragma unroll
  for (int v = 0; v < 16; ++v) {
    int f = v * 256 + tid;
    int d = f >> 6, tt = f & 63;
    ts[d][tt] = aggT[((size_t)b * DK + d) * LQ + t0 + tt];
  }
  __syncthreads();

#pragma unroll
  for (int v = 0; v < 128; ++v) {
    int f = v * 256 + tid;
    int tt = f >> 9, c = f & 511;
    out[((size_t)b * LQ + t0 + tt) * (8 * DK) + c] = ts[c & 63][tt];
  }
}

// ---------------------------------------------------------------------------
// ws layout (floats), peak 7M = 28 MB:
//   [0, 2M)   qd [256][8192] q duplicated   -> after topk: lagB/wtB
//   [2M, 3M)  kp [256][4096]                -> after corr: vp (projv)
//   [3M, 7M)  corrP [4][256][4096]          -> after topk: aggT
// ---------------------------------------------------------------------------
extern "C" void kernel_launch(void* const* d_in, const int* in_sizes, int n_in,
                              void* d_out, int out_size, void* d_ws, size_t ws_size,
                              hipStream_t stream) {
  const float* q_in = (const float*)d_in[0];
  const float* k_in = (const float*)d_in[1];
  const float* v_in = (const float*)d_in[2];
  const float* Wq   = (const float*)d_in[3];
  const float* bq   = (const float*)d_in[4];
  float* out = (float*)d_out;
  float* ws  = (float*)d_ws;

  const size_t M = (size_t)NROWS * LQ;        // 1,048,576 floats
  float* qd    = ws;                          // [0, 2M)
  float* kp    = ws + 2 * M;                  // [2M, 3M)
  float* corrP = ws + 3 * M;                  // [3M, 7M)
  int*   lagB  = (int*)ws;                    // reuse qd (dead after corr)
  float* wtB   = ws + NROWS * TOPK;
  float* vp    = kp;                          // reuse kp (dead after corr)
  float* aggT  = corrP;                       // reuse corrP part0 (dead after topk)

  projqk_kernel<<<dim3(256, 1, 2), 256, 0, stream>>>(q_in, k_in, Wq, bq, qd, kp);
  corr_kernel<<<dim3(4, NROWS), 256, 0, stream>>>(qd, kp, corrP);
  topk_kernel<<<NROWS, 256, 0, stream>>>(corrP, lagB, wtB);
  projv_kernel<<<dim3(256, 1, 1), 256, 0, stream>>>(v_in, Wq, bq, vp);
  agg_kernel<<<NROWS, 256, 0, stream>>>(vp, lagB, wtB, aggT);
  trans_kernel<<<dim3(LQ / 64, BQ), 256, 0, stream>>>(aggT, out);
}

// Round 6
// 186.435 us; speedup vs baseline: 1.7942x; 1.3945x over previous
//
#include <hip/hip_runtime.h>
#include <hip/hip_bf16.h>

#define BQ 4
#define LQ 4096
#define DM 512
#define DK 64
#define NROWS (BQ * DK)        // 256
#define TOPK 16
#define CAND 32

typedef __attribute__((ext_vector_type(8))) short short8v;
typedef __attribute__((ext_vector_type(16))) float f32x16;

// async global->LDS, 16B per lane; LDS dest is wave-uniform base + lane*16B.
__device__ __forceinline__ void gl_lds16(const float* g, float* s) {
  auto g1 = (const __attribute__((address_space(1))) float*)(uintptr_t)g;
  auto s3 = (__attribute__((address_space(3))) float*)(uint32_t)(uintptr_t)s;
  __builtin_amdgcn_global_load_lds(g1, s3, 16, 0, 0);
}

__device__ __forceinline__ unsigned short f2bf(float x) {
  unsigned u = __builtin_bit_cast(unsigned, x);
  return (unsigned short)((u + 0x7FFFu + ((u >> 16) & 1u)) >> 16);
}

// ---------------------------------------------------------------------------
// Kernel 1: projection p[b*64+j][i] = sum_k x[b*4096+i][k]*Wq[k][j] + bq[j]
// (r5 body, DUP removed; z selects q/k/v -> ws + z*M)
// ---------------------------------------------------------------------------
__global__ __launch_bounds__(256) void proj_kernel(
    const float* __restrict__ q_in, const float* __restrict__ k_in,
    const float* __restrict__ v_in, const float* __restrict__ Wq,
    const float* __restrict__ bq, float* __restrict__ ws) {
  const float* x = blockIdx.z == 0 ? q_in : (blockIdx.z == 1 ? k_in : v_in);
  float* outp = ws + (size_t)blockIdx.z * (size_t)(NROWS * LQ);

  __shared__ __align__(16) float smem[8192];   // xs[4096] | wl[4096]
  float* xs = smem;
  float* wl = smem + 4096;

  const int tid = threadIdx.x;
  const int lane = tid & 63, wvi = tid >> 6;
  const int tx = tid & 15, ty = tid >> 4;
  const int R0 = blockIdx.x * 64;

  float acc[4][4];
#pragma unroll
  for (int r = 0; r < 4; ++r)
#pragma unroll
    for (int c = 0; c < 4; ++c) acc[r][c] = 0.f;

  const int qg = lane & 15, r4 = lane >> 4;
  const int colw = tid & 63, kseg = tid >> 6;

  for (int kc = 0; kc < DM; kc += 64) {
#pragma unroll
    for (int is = 0; is < 4; ++is) {
      int rloc = wvi * 16 + is * 4 + r4;
      gl_lds16(&x[(size_t)(R0 + rloc) * DM + kc + ((qg ^ (rloc & 7)) << 2)],
               &xs[(wvi * 16 + is * 4) * 64]);
    }
    float wv16[16];
#pragma unroll
    for (int u = 0; u < 16; ++u)
      wv16[u] = Wq[(size_t)(kc + kseg * 16 + u) * DK + colw];
#pragma unroll
    for (int kk4 = 0; kk4 < 4; ++kk4) {
      int phys = ((kseg * 4 + kk4) ^ (colw & 7)) << 2;
      float4 o;
      o.x = wv16[kk4 * 4]; o.y = wv16[kk4 * 4 + 1];
      o.z = wv16[kk4 * 4 + 2]; o.w = wv16[kk4 * 4 + 3];
      *reinterpret_cast<float4*>(&wl[colw * 64 + phys]) = o;
    }
    __syncthreads();

    const int c0 = tx * 4, s0 = c0 & 7, s1 = (c0 + 1) & 7,
              s2 = (c0 + 2) & 7, s3 = (c0 + 3) & 7;
#pragma unroll
    for (int kq = 0; kq < 16; ++kq) {
      const int kqe = kq ^ tx;
      float4 xv[4], wv[4];
#pragma unroll
      for (int rr = 0; rr < 4; ++rr) {
        int rw = ty * 4 + rr;
        xv[rr] = *reinterpret_cast<const float4*>(
            &xs[rw * 64 + ((kqe ^ (rw & 7)) << 2)]);
      }
      wv[0] = *reinterpret_cast<const float4*>(&wl[(c0 + 0) * 64 + ((kqe ^ s0) << 2)]);
      wv[1] = *reinterpret_cast<const float4*>(&wl[(c0 + 1) * 64 + ((kqe ^ s1) << 2)]);
      wv[2] = *reinterpret_cast<const float4*>(&wl[(c0 + 2) * 64 + ((kqe ^ s2) << 2)]);
      wv[3] = *reinterpret_cast<const float4*>(&wl[(c0 + 3) * 64 + ((kqe ^ s3) << 2)]);
#pragma unroll
      for (int rr = 0; rr < 4; ++rr)
#pragma unroll
        for (int cc = 0; cc < 4; ++cc) {
          acc[rr][cc] = fmaf(xv[rr].x, wv[cc].x, acc[rr][cc]);
          acc[rr][cc] = fmaf(xv[rr].y, wv[cc].y, acc[rr][cc]);
          acc[rr][cc] = fmaf(xv[rr].z, wv[cc].z, acc[rr][cc]);
          acc[rr][cc] = fmaf(xv[rr].w, wv[cc].w, acc[rr][cc]);
        }
    }
    __syncthreads();
  }

  float* tr = smem;  // [64][65]
  float bb[4];
#pragma unroll
  for (int cc = 0; cc < 4; ++cc) bb[cc] = bq[tx * 4 + cc];
#pragma unroll
  for (int rr = 0; rr < 4; ++rr)
#pragma unroll
    for (int cc = 0; cc < 4; ++cc)
      tr[(tx * 4 + cc) * 65 + ty * 4 + rr] = acc[rr][cc] + bb[cc];
  __syncthreads();
  const int b = R0 >> 12, i0 = R0 & (LQ - 1);
#pragma unroll
  for (int v = 0; v < 16; ++v) {
    int f = v * 256 + tid;
    int j = f >> 6, i = f & 63;
    outp[((size_t)b * DK + j) * LQ + i0 + i] = tr[j * 65 + i];
  }
}

// ---------------------------------------------------------------------------
// Kernel 2 v5: MFMA Toeplitz correlation (bf16 screen, fp32 refine later).
// corr[32m+n] = sum_kk k[(kk-32m)%L] * q[(kk+n)%L]
// Block = 1 row, 4 waves = 4 K-parts (kk in [1024w,1024w+1024)).
// Wave: 4 C-tiles (32x32), M-tile M covers tau [1024M, 1024M+1024).
// A-frag (k): lane 8 consec bf16 at ((16J - 1024M - 32*(l&31) + 8*(l>>5))
//   & 4095), XOR-quad-swizzled LDS -> 1 ds_read_b128.
// B-frag (q): lane 8 consec bf16 at s = 16J + (l&31) + 8*(l>>5), from
//   4 shift-copies (copy r: qs[r][e]=q[(e+r)%L]) -> 2 aligned ds_read_b64.
// No barriers in K-loop (LDS read-only after staging).
// ---------------------------------------------------------------------------
__global__ __launch_bounds__(256) void corr_kernel(
    const float* __restrict__ qp, const float* __restrict__ kp,
    float* __restrict__ corrP) {
  const int row = blockIdx.x;
  const int tid = threadIdx.x;
  __shared__ __align__(16) short qs[3 * 4112 + 4096];  // 4 copies, stride 4112
  __shared__ __align__(16) short ks[4096];

  const float* qr = qp + ((size_t)row << 12);
  const float* kr = kp + ((size_t)row << 12);

  // ---- staging ----
  {
    const float4* q4 = (const float4*)qr;
    float f[20];
#pragma unroll
    for (int c = 0; c < 4; ++c) {
      float4 v = q4[tid * 4 + c];
      f[c * 4 + 0] = v.x; f[c * 4 + 1] = v.y;
      f[c * 4 + 2] = v.z; f[c * 4 + 3] = v.w;
    }
    {
      float4 v = (tid == 255) ? q4[0] : q4[tid * 4 + 4];
      f[16] = v.x; f[17] = v.y; f[18] = v.z; f[19] = v.w;
    }
#pragma unroll
    for (int r = 0; r < 4; ++r) {
      short8v o0, o1;
#pragma unroll
      for (int i = 0; i < 8; ++i) {
        o0[i] = (short)f2bf(f[i + r]);
        o1[i] = (short)f2bf(f[8 + i + r]);
      }
      *(short8v*)(&qs[r * 4112 + tid * 16]) = o0;
      *(short8v*)(&qs[r * 4112 + tid * 16 + 8]) = o1;
    }
    const float4* k4 = (const float4*)kr;
    float g[16];
#pragma unroll
    for (int c = 0; c < 4; ++c) {
      float4 w = k4[tid * 4 + c];
      g[c * 4 + 0] = w.x; g[c * 4 + 1] = w.y;
      g[c * 4 + 2] = w.z; g[c * 4 + 3] = w.w;
    }
#pragma unroll
    for (int h = 0; h < 2; ++h) {
      int Q = 2 * tid + h;
      int Qs = Q ^ ((Q >> 3) & 7);
      short8v o;
#pragma unroll
      for (int i = 0; i < 8; ++i) o[i] = (short)f2bf(g[h * 8 + i]);
      *(short8v*)(&ks[Qs << 3]) = o;
    }
  }
  __syncthreads();

  const int l = tid & 63, wv = tid >> 6;
  const int Oq = ((8 * (l >> 5) - 32 * (l & 31)) & 4095) >> 3;  // k quad off
  const int rB = (l & 31) & 3;
  const int Ce = (l & 31) + 8 * (l >> 5) - rB;
  const short* qb = qs + rB * 4112;

  f32x16 acc[4];
#pragma unroll
  for (int M = 0; M < 4; ++M)
#pragma unroll
    for (int i = 0; i < 16; ++i) acc[M][i] = 0.f;

  const int J0 = wv * 64;
#pragma unroll 2
  for (int jb = 0; jb < 64; ++jb) {
    const int J = J0 + jb;
    int e1 = (Ce + 16 * J) & 4095;
    int e2 = (e1 + 4) & 4095;
    uint2 blo = *(const uint2*)(qb + e1);
    uint2 bhi = *(const uint2*)(qb + e2);
    int4 bi; bi.x = blo.x; bi.y = blo.y; bi.z = bhi.x; bi.w = bhi.y;
    short8v bf = __builtin_bit_cast(short8v, bi);
    const int Dq = 2 * J;
#pragma unroll
    for (int M = 0; M < 4; ++M) {
      int Q = (Oq + Dq - 128 * M) & 511;
      Q ^= (Q >> 3) & 7;
      short8v af = *(const short8v*)(&ks[Q << 3]);
      asm volatile("v_mfma_f32_32x32x16_bf16 %0, %1, %2, %0"
                   : "+v"(acc[M]) : "v"(af), "v"(bf));
    }
  }

  // MFMA->VALU/VMEM hazard padding, then store.
  asm volatile("s_nop 7\n\ts_nop 7\n\ts_nop 7" ::: "memory");
  float* cp = corrP + (((size_t)wv * NROWS + row) << 12);
  const int cn = l & 31, ch4 = (l >> 5) * 4;
#pragma unroll
  for (int M = 0; M < 4; ++M)
#pragma unroll
    for (int r = 0; r < 16; ++r)
      cp[(M << 10) + 32 * ((r & 3) + 8 * (r >> 2) + ch4) + cn] = acc[M][r];
}

// ---------------------------------------------------------------------------
// Kernel 3: top-32 screen on approx corr -> exact fp32 refine -> top-16
// (jax tie-break: smaller index on equal) + softmax.
// lw layout per row (4096 floats stride): [0..16) lag ints, [16..32) weights.
// ---------------------------------------------------------------------------
__global__ __launch_bounds__(256) void topk_kernel(
    const float* __restrict__ corrP, const float* __restrict__ qp,
    const float* __restrict__ kp, float* __restrict__ lw) {
  const int row = blockIdx.x, tid = threadIdx.x;
  const float* c0 = corrP + (size_t)row * LQ;
  const size_t PS = (size_t)NROWS * LQ;

  __shared__ __align__(16) float kf[LQ];
  __shared__ __align__(16) float qf[LQ];
  __shared__ float rv[4]; __shared__ int ri[4];
  __shared__ float sval[CAND]; __shared__ int sidx[CAND];
  __shared__ float rS[CAND];
  __shared__ float ordv[TOPK]; __shared__ int ordl[TOPK];

  // stage fp32 rows for refine
  {
    const float4* k4 = (const float4*)(kp + ((size_t)row << 12));
    const float4* q4 = (const float4*)(qp + ((size_t)row << 12));
    for (int x = tid; x < 1024; x += 256) {
      ((float4*)kf)[x] = k4[x];
      ((float4*)qf)[x] = q4[x];
    }
  }

  float v[16]; int ix[16];
#pragma unroll
  for (int m = 0; m < 16; ++m) {
    int tau = m * 256 + tid;
    float s = c0[tau] + c0[PS + tau] + c0[2 * PS + tau] + c0[3 * PS + tau];
    v[m] = fabsf(s);
    ix[m] = tau;
  }

  const int lane = tid & 63, wid = tid >> 6;
  for (int round = 0; round < CAND; ++round) {
    float bv = -1.f; int bi = 0x7fffffff;
#pragma unroll
    for (int m = 0; m < 16; ++m)
      if (v[m] > bv || (v[m] == bv && ix[m] < bi)) { bv = v[m]; bi = ix[m]; }
#pragma unroll
    for (int off = 32; off > 0; off >>= 1) {
      float ov = __shfl_down(bv, off);
      int oi = __shfl_down(bi, off);
      if (ov > bv || (ov == bv && oi < bi)) { bv = ov; bi = oi; }
    }
    if (lane == 0) { rv[wid] = bv; ri[wid] = bi; }
    __syncthreads();
    if (tid == 0) {
      float fv = rv[0]; int fi = ri[0];
      for (int w = 1; w < 4; ++w)
        if (rv[w] > fv || (rv[w] == fv && ri[w] < fi)) { fv = rv[w]; fi = ri[w]; }
      sval[round] = fv; sidx[round] = fi;
    }
    __syncthreads();
    int widx = sidx[round];
#pragma unroll
    for (int m = 0; m < 16; ++m)
      if (ix[m] == widx) v[m] = -1.f;
  }

  // exact fp32 refine: 8 threads per candidate
  {
    const int ci = tid >> 3, sub = tid & 7;
    const int lag = sidx[ci];
    float S = 0.f;
#pragma unroll 4
    for (int it = 0; it < 512; ++it) {
      int t = it * 8 + sub;
      S = fmaf(kf[t], qf[(t + lag) & (LQ - 1)], S);
    }
    S += __shfl_xor(S, 1);
    S += __shfl_xor(S, 2);
    S += __shfl_xor(S, 4);
    if (sub == 0) rS[ci] = S;
  }
  __syncthreads();

  // rank among 32 by (|S| desc, idx asc); keep top-16
  if (tid < CAND) {
    float vi = fabsf(rS[tid]); int ii = sidx[tid];
    int rank = 0;
    for (int j = 0; j < CAND; ++j) {
      float vj = fabsf(rS[j]);
      rank += (vj > vi) || (vj == vi && sidx[j] < ii);
    }
    if (rank < TOPK) { ordv[rank] = vi; ordl[rank] = ii; }
  }
  __syncthreads();

  if (tid == 0) {
    float m0 = ordv[0], s = 0.f, e[TOPK];
    for (int k = 0; k < TOPK; ++k) { e[k] = expf(ordv[k] - m0); s += e[k]; }
    float inv = 1.f / s;
    int* ip = (int*)(lw + (size_t)row * LQ);
    for (int k = 0; k < TOPK; ++k) {
      ip[k] = ordl[k];
      ((float*)ip)[TOPK + k] = e[k] * inv;
    }
  }
}

// ---------------------------------------------------------------------------
// Kernel 4: aggregation  aggT[row][t] = sum_k w_k * v[row][(t+lag_k)%L]
// ---------------------------------------------------------------------------
__global__ void agg_kernel(const float* __restrict__ vpT,
                           const float* __restrict__ lw,
                           float* __restrict__ aggT) {
  const int row = blockIdx.x, tid = threadIdx.x;
  __shared__ __align__(16) float vr[2 * LQ];
  __shared__ float w[TOPK]; __shared__ int lg[TOPK];

  const float* v0 = vpT + (size_t)row * LQ;
  for (int x = tid; x < LQ; x += 256) {
    float val = v0[x];
    vr[x] = val; vr[x + LQ] = val;
  }
  if (tid < TOPK) {
    const float* lwr = lw + (size_t)row * LQ;
    lg[tid] = ((const int*)lwr)[tid];
    w[tid] = lwr[TOPK + tid];
  }
  __syncthreads();

  float wr[TOPK]; int lr[TOPK];
#pragma unroll
  for (int k = 0; k < TOPK; ++k) { wr[k] = w[k]; lr[k] = lg[k]; }

  for (int m = 0; m < 16; ++m) {
    int t = m * 256 + tid;
    float a = 0.f;
#pragma unroll
    for (int k = 0; k < TOPK; ++k) a = fmaf(wr[k], vr[t + lr[k]], a);
    aggT[(size_t)row * LQ + t] = a;
  }
}

// ---------------------------------------------------------------------------
// Kernel 5: transpose + head-broadcast  out[b][t][c] = aggT[b][c&63][t]
// ---------------------------------------------------------------------------
__global__ void trans_kernel(const float* __restrict__ aggT,
                             float* __restrict__ out) {
  const int b = blockIdx.y;
  const int t0 = blockIdx.x * 64;
  const int tid = threadIdx.x;
  __shared__ float ts[64][65];

#pragma unroll
  for (int v = 0; v < 16; ++v) {
    int f = v * 256 + tid;
    int d = f >> 6, tt = f & 63;
    ts[d][tt] = aggT[((size_t)b * DK + d) * LQ + t0 + tt];
  }
  __syncthreads();

#pragma unroll
  for (int v = 0; v < 128; ++v) {
    int f = v * 256 + tid;
    int tt = f >> 9, c = f & 511;
    out[((size_t)b * LQ + t0 + tt) * (8 * DK) + c] = ts[c & 63][tt];
  }
}

// ---------------------------------------------------------------------------
// ws layout (floats), peak 7M = 28 MB (proven budget):
//   [0,1M) qp   [1M,2M) kp   [2M,3M) vp
//   [3M,7M) corrP[4][256][4096]
//     - aggT reuses corrP[0] ([3M,4M)) after topk
//     - lag/wt live in corrP[3] ([6M,7M)): row r owns [r*4096, +32)
// ---------------------------------------------------------------------------
extern "C" void kernel_launch(void* const* d_in, const int* in_sizes, int n_in,
                              void* d_out, int out_size, void* d_ws, size_t ws_size,
                              hipStream_t stream) {
  const float* q_in = (const float*)d_in[0];
  const float* k_in = (const float*)d_in[1];
  const float* v_in = (const float*)d_in[2];
  const float* Wq   = (const float*)d_in[3];
  const float* bq   = (const float*)d_in[4];
  float* out = (float*)d_out;
  float* ws  = (float*)d_ws;

  const size_t M = (size_t)NROWS * LQ;        // 1,048,576 floats
  float* qp    = ws;
  float* kp    = ws + M;
  float* vp    = ws + 2 * M;
  float* corrP = ws + 3 * M;
  float* aggT  = corrP;                       // reuse corrP[0] after topk
  float* lw    = ws + 6 * M;                  // inside corrP[3], per-row owned

  proj_kernel<<<dim3(256, 1, 3), 256, 0, stream>>>(q_in, k_in, v_in, Wq, bq, ws);
  corr_kernel<<<NROWS, 256, 0, stream>>>(qp, kp, corrP);
  topk_kernel<<<NROWS, 256, 0, stream>>>(corrP, qp, kp, lw);
  agg_kernel<<<NROWS, 256, 0, stream>>>(vp, lw, aggT);
  trans_kernel<<<dim3(LQ / 64, BQ), 256, 0, stream>>>(aggT, out);
}

// Round 7
// 131.304 us; speedup vs baseline: 2.5475x; 1.4199x over previous
//
#include <hip/hip_runtime.h>
#include <hip/hip_bf16.h>

#define BQ 4
#define LQ 4096
#define DM 512
#define DK 64
#define NROWS (BQ * DK)        // 256
#define TOPK 16
#define CAND 32

typedef __attribute__((ext_vector_type(4))) short short4v;
typedef __attribute__((ext_vector_type(8))) short short8v;
typedef __attribute__((ext_vector_type(16))) float f32x16;

__device__ __forceinline__ unsigned short f2bf(float x) {
  unsigned u = __builtin_bit_cast(unsigned, x);
  return (unsigned short)((u + 0x7FFFu + ((u >> 16) & 1u)) >> 16);
}
__device__ __forceinline__ float bf2f(unsigned short h) {
  unsigned u = ((unsigned)h) << 16;
  return __builtin_bit_cast(float, u);
}

// ---------------------------------------------------------------------------
// Kernel 1 v3: projection via split-bf16 MFMA (3 products: hh, hl, lh).
// pT[b*64+j][i] = sum_k x[b*4096+i][k]*Wq[k][j] + bq[j]
// grid (128,1,3), block 256 = 4 waves. Block tile 128 rows x 64 cols.
// Wave w: 1 M-tile (rows R0+32w..+32) x 2 N-tiles. kc-chunk = 64.
// LDS bf16 planes stride 72/row, quad-XOR swizzle q^(2*((row>>3)&3)) ->
// uniform 8 lanes/bank-group on ds_read_b128 (the b128 floor).
// Fragment mappings reused from the r6-validated corr kernel:
//   A: lane row=l&31, k=8*(l>>5)+i consec; B: lane col=l&31, k consec;
//   C: row=(r&3)+8*(r>>2)+4*(l>>5), col=l&31.
// ---------------------------------------------------------------------------
__global__ __launch_bounds__(256) void proj_kernel(
    const float* __restrict__ q_in, const float* __restrict__ k_in,
    const float* __restrict__ v_in, const float* __restrict__ Wq,
    const float* __restrict__ bq, float* __restrict__ ws) {
  const float* x = blockIdx.z == 0 ? q_in : (blockIdx.z == 1 ? k_in : v_in);
  float* outp = ws + (size_t)blockIdx.z * (size_t)(NROWS * LQ);

  __shared__ __align__(16) short sm[27648];   // 55296 B
  short* xh = sm;            // [128][72]
  short* xl = sm + 9216;
  short* wh = sm + 18432;    // [64][72]
  short* wl = sm + 23040;

  const int tid = threadIdx.x;
  const int l = tid & 63, wv = tid >> 6;
  const int R0 = blockIdx.x * 128;

  const int srow = tid >> 1;           // x staging row 0..127
  const int sp0 = (tid & 1) * 8;       // first float4 slot (of 16 per row)
  const int wcol = tid & 63;           // W staging col
  const int wk0 = (tid >> 6) * 16;     // W staging k base within chunk

  f32x16 acc[2];
#pragma unroll
  for (int nt = 0; nt < 2; ++nt)
#pragma unroll
    for (int i = 0; i < 16; ++i) acc[nt][i] = 0.f;

  float4 xr[8];
  float wr[16];
#pragma unroll
  for (int c = 0; c < 8; ++c)
    xr[c] = *reinterpret_cast<const float4*>(
        &x[(size_t)(R0 + srow) * DM + (sp0 + c) * 4]);
#pragma unroll
  for (int u = 0; u < 16; ++u)
    wr[u] = Wq[(size_t)(wk0 + u) * DK + wcol];

  const int arow = wv * 32 + (l & 31);
  const int qn = l >> 5;
  const int aswz = 2 * ((arow >> 3) & 3);
  const int bc0 = l & 31;
  const int bswz0 = 2 * (((0 + bc0) >> 3) & 3);
  const int bswz1 = 2 * (((32 + bc0) >> 3) & 3);

  for (int kc = 0; kc < DM; kc += 64) {
    __syncthreads();   // previous chunk's readers done
    // ---- stage x (hi/lo bf16) ----
#pragma unroll
    for (int c = 0; c < 8; ++c) {
      int f4 = sp0 + c;
      int qd = (f4 >> 1) ^ (2 * ((srow >> 3) & 3));
      int base = srow * 72 + qd * 8 + (f4 & 1) * 4;
      float vv[4] = {xr[c].x, xr[c].y, xr[c].z, xr[c].w};
      short4v hi, lo;
#pragma unroll
      for (int i = 0; i < 4; ++i) {
        unsigned short h = f2bf(vv[i]);
        hi[i] = (short)h;
        lo[i] = (short)f2bf(vv[i] - bf2f(h));
      }
      *reinterpret_cast<short4v*>(xh + base) = hi;
      *reinterpret_cast<short4v*>(xl + base) = lo;
    }
    // ---- stage W^T (hi/lo bf16) ----
#pragma unroll
    for (int qq = 0; qq < 2; ++qq) {
      int qd = ((wk0 >> 3) + qq) ^ (2 * ((wcol >> 3) & 3));
      int base = wcol * 72 + qd * 8;
      short8v hi, lo;
#pragma unroll
      for (int i = 0; i < 8; ++i) {
        float vv = wr[qq * 8 + i];
        unsigned short h = f2bf(vv);
        hi[i] = (short)h;
        lo[i] = (short)f2bf(vv - bf2f(h));
      }
      *reinterpret_cast<short8v*>(wh + base) = hi;
      *reinterpret_cast<short8v*>(wl + base) = lo;
    }
    __syncthreads();
    // ---- issue next chunk's global loads early (T14) ----
    if (kc + 64 < DM) {
#pragma unroll
      for (int c = 0; c < 8; ++c)
        xr[c] = *reinterpret_cast<const float4*>(
            &x[(size_t)(R0 + srow) * DM + kc + 64 + (sp0 + c) * 4]);
#pragma unroll
      for (int u = 0; u < 16; ++u)
        wr[u] = Wq[(size_t)(kc + 64 + wk0 + u) * DK + wcol];
    }
    // ---- compute 4 K-steps x 2 N-tiles x 3 products ----
#pragma unroll
    for (int ks = 0; ks < 4; ++ks) {
      int qA = (2 * ks + qn) ^ aswz;
      short8v ah = *reinterpret_cast<const short8v*>(xh + arow * 72 + qA * 8);
      short8v al_ = *reinterpret_cast<const short8v*>(xl + arow * 72 + qA * 8);
      {
        int qB = (2 * ks + qn) ^ bswz0;
        short8v bh = *reinterpret_cast<const short8v*>(wh + bc0 * 72 + qB * 8);
        short8v bl_ = *reinterpret_cast<const short8v*>(wl + bc0 * 72 + qB * 8);
        asm volatile("v_mfma_f32_32x32x16_bf16 %0, %1, %2, %0"
                     : "+v"(acc[0]) : "v"(ah), "v"(bh));
        asm volatile("v_mfma_f32_32x32x16_bf16 %0, %1, %2, %0"
                     : "+v"(acc[0]) : "v"(ah), "v"(bl_));
        asm volatile("v_mfma_f32_32x32x16_bf16 %0, %1, %2, %0"
                     : "+v"(acc[0]) : "v"(al_), "v"(bh));
      }
      {
        int qB = (2 * ks + qn) ^ bswz1;
        short8v bh = *reinterpret_cast<const short8v*>(wh + (32 + bc0) * 72 + qB * 8);
        short8v bl_ = *reinterpret_cast<const short8v*>(wl + (32 + bc0) * 72 + qB * 8);
        asm volatile("v_mfma_f32_32x32x16_bf16 %0, %1, %2, %0"
                     : "+v"(acc[1]) : "v"(ah), "v"(bh));
        asm volatile("v_mfma_f32_32x32x16_bf16 %0, %1, %2, %0"
                     : "+v"(acc[1]) : "v"(ah), "v"(bl_));
        asm volatile("v_mfma_f32_32x32x16_bf16 %0, %1, %2, %0"
                     : "+v"(acc[1]) : "v"(al_), "v"(bh));
      }
    }
  }

  // ---- epilogue: bias + per-tile LDS transpose + coalesced b64 stores ----
  asm volatile("s_nop 7\n\ts_nop 7\n\ts_nop 7" ::: "memory");
  __syncthreads();
  float* ts = (float*)sm;   // 8 areas of [32][34] f32 = 34816 B
  const int b = R0 >> 12, i0 = R0 & (LQ - 1);
  float bb[2] = {bq[l & 31], bq[32 + (l & 31)]};
#pragma unroll
  for (int nt = 0; nt < 2; ++nt) {
    float* area = ts + (wv * 2 + nt) * 1088;
#pragma unroll
    for (int r = 0; r < 16; ++r) {
      int io = (r & 3) + 8 * (r >> 2) + 4 * (l >> 5);
      area[(l & 31) * 34 + io] = acc[nt][r] + bb[nt];
    }
  }
  __syncthreads();
  const int e = l & 15, jg = l >> 4;
#pragma unroll
  for (int nt = 0; nt < 2; ++nt) {
    const float* area = ts + (wv * 2 + nt) * 1088;
#pragma unroll
    for (int p = 0; p < 8; ++p) {
      int jj = jg * 8 + p;
      float2 v = *reinterpret_cast<const float2*>(area + jj * 34 + e * 2);
      *reinterpret_cast<float2*>(
          &outp[((size_t)b * DK + nt * 32 + jj) * LQ + i0 + wv * 32 + e * 2]) = v;
    }
  }
}

// ---------------------------------------------------------------------------
// Kernel 2 v6: MFMA Toeplitz correlation + in-block K-partial reduction.
// corrS[row][tau] = sum_t k[t] * q[t+tau mod L]   (single 4 MB buffer)
// ---------------------------------------------------------------------------
__global__ __launch_bounds__(256) void corr_kernel(
    const float* __restrict__ qp, const float* __restrict__ kp,
    float* __restrict__ corrS) {
  const int row = blockIdx.x;
  const int tid = threadIdx.x;
  __shared__ __align__(16) short qs[3 * 4112 + 4096];  // 4 copies, stride 4112
  __shared__ __align__(16) short ks[4096];

  const float* qr = qp + ((size_t)row << 12);
  const float* kr = kp + ((size_t)row << 12);

  // ---- staging ----
  {
    const float4* q4 = (const float4*)qr;
    float f[20];
#pragma unroll
    for (int c = 0; c < 4; ++c) {
      float4 v = q4[tid * 4 + c];
      f[c * 4 + 0] = v.x; f[c * 4 + 1] = v.y;
      f[c * 4 + 2] = v.z; f[c * 4 + 3] = v.w;
    }
    {
      float4 v = (tid == 255) ? q4[0] : q4[tid * 4 + 4];
      f[16] = v.x; f[17] = v.y; f[18] = v.z; f[19] = v.w;
    }
#pragma unroll
    for (int r = 0; r < 4; ++r) {
      short8v o0, o1;
#pragma unroll
      for (int i = 0; i < 8; ++i) {
        o0[i] = (short)f2bf(f[i + r]);
        o1[i] = (short)f2bf(f[8 + i + r]);
      }
      *(short8v*)(&qs[r * 4112 + tid * 16]) = o0;
      *(short8v*)(&qs[r * 4112 + tid * 16 + 8]) = o1;
    }
    const float4* k4 = (const float4*)kr;
    float g[16];
#pragma unroll
    for (int c = 0; c < 4; ++c) {
      float4 w = k4[tid * 4 + c];
      g[c * 4 + 0] = w.x; g[c * 4 + 1] = w.y;
      g[c * 4 + 2] = w.z; g[c * 4 + 3] = w.w;
    }
#pragma unroll
    for (int h = 0; h < 2; ++h) {
      int Q = 2 * tid + h;
      int Qs = Q ^ ((Q >> 3) & 7);
      short8v o;
#pragma unroll
      for (int i = 0; i < 8; ++i) o[i] = (short)f2bf(g[h * 8 + i]);
      *(short8v*)(&ks[Qs << 3]) = o;
    }
  }
  __syncthreads();

  const int l = tid & 63, wv = tid >> 6;
  const int Oq = ((8 * (l >> 5) - 32 * (l & 31)) & 4095) >> 3;
  const int rB = (l & 31) & 3;
  const int Ce = (l & 31) + 8 * (l >> 5) - rB;
  const short* qb = qs + rB * 4112;

  f32x16 acc[4];
#pragma unroll
  for (int M = 0; M < 4; ++M)
#pragma unroll
    for (int i = 0; i < 16; ++i) acc[M][i] = 0.f;

  const int J0 = wv * 64;
#pragma unroll 2
  for (int jb = 0; jb < 64; ++jb) {
    const int J = J0 + jb;
    int e1 = (Ce + 16 * J) & 4095;
    int e2 = (e1 + 4) & 4095;
    uint2 blo = *(const uint2*)(qb + e1);
    uint2 bhi = *(const uint2*)(qb + e2);
    int4 bi; bi.x = blo.x; bi.y = blo.y; bi.z = bhi.x; bi.w = bhi.y;
    short8v bf = __builtin_bit_cast(short8v, bi);
    const int Dq = 2 * J;
#pragma unroll
    for (int M = 0; M < 4; ++M) {
      int Q = (Oq + Dq - 128 * M) & 511;
      Q ^= (Q >> 3) & 7;
      short8v af = *(const short8v*)(&ks[Q << 3]);
      asm volatile("v_mfma_f32_32x32x16_bf16 %0, %1, %2, %0"
                   : "+v"(acc[M]) : "v"(af), "v"(bf));
    }
  }

  // ---- in-block reduction of the 4 wave K-partials (reuse qs as f32) ----
  asm volatile("s_nop 7\n\ts_nop 7\n\ts_nop 7" ::: "memory");
  __syncthreads();
  float* red = (float*)qs;   // 8216 floats available, need 8192
  const int strip = (wv & 1) * 4096;
  const int ch4 = (l >> 5) * 4, cn = l & 31;
  if (wv < 2) {
#pragma unroll
    for (int M = 0; M < 4; ++M)
#pragma unroll
      for (int r = 0; r < 16; ++r)
        red[strip + (M << 10) + 32 * ((r & 3) + 8 * (r >> 2) + ch4) + cn] =
            acc[M][r];
  }
  __syncthreads();
  if (wv >= 2) {
#pragma unroll
    for (int M = 0; M < 4; ++M)
#pragma unroll
      for (int r = 0; r < 16; ++r)
        red[strip + (M << 10) + 32 * ((r & 3) + 8 * (r >> 2) + ch4) + cn] +=
            acc[M][r];
  }
  __syncthreads();
  float* cs = corrS + ((size_t)row << 12);
#pragma unroll
  for (int c = 0; c < 4; ++c) {
    int i = tid * 16 + c * 4;
    float4 a = *(const float4*)(&red[i]);
    float4 b2 = *(const float4*)(&red[4096 + i]);
    float4 o;
    o.x = a.x + b2.x; o.y = a.y + b2.y; o.z = a.z + b2.z; o.w = a.w + b2.w;
    *(float4*)(&cs[i]) = o;
  }
}

// ---------------------------------------------------------------------------
// Kernel 3: top-32 screen on approx corr -> exact fp32 refine -> top-16
// (jax tie-break: smaller index on equal) + softmax.
// lw per row: [0..16) lag ints, [16..32) weights (stride 32).
// ---------------------------------------------------------------------------
__global__ __launch_bounds__(256) void topk_kernel(
    const float* __restrict__ corrS, const float* __restrict__ qp,
    const float* __restrict__ kp, float* __restrict__ lw) {
  const int row = blockIdx.x, tid = threadIdx.x;
  const float* c0 = corrS + (size_t)row * LQ;

  __shared__ __align__(16) float kf[LQ];
  __shared__ __align__(16) float qf[LQ];
  __shared__ float rv[4]; __shared__ int ri[4];
  __shared__ float sval[CAND]; __shared__ int sidx[CAND];
  __shared__ float rS[CAND];
  __shared__ float ordv[TOPK]; __shared__ int ordl[TOPK];

  {
    const float4* k4 = (const float4*)(kp + ((size_t)row << 12));
    const float4* q4 = (const float4*)(qp + ((size_t)row << 12));
    for (int x = tid; x < 1024; x += 256) {
      ((float4*)kf)[x] = k4[x];
      ((float4*)qf)[x] = q4[x];
    }
  }

  float v[16]; int ix[16];
#pragma unroll
  for (int m = 0; m < 16; ++m) {
    int tau = m * 256 + tid;
    v[m] = fabsf(c0[tau]);
    ix[m] = tau;
  }

  const int lane = tid & 63, wid = tid >> 6;
  for (int round = 0; round < CAND; ++round) {
    float bv = -1.f; int bi = 0x7fffffff;
#pragma unroll
    for (int m = 0; m < 16; ++m)
      if (v[m] > bv || (v[m] == bv && ix[m] < bi)) { bv = v[m]; bi = ix[m]; }
#pragma unroll
    for (int off = 32; off > 0; off >>= 1) {
      float ov = __shfl_down(bv, off);
      int oi = __shfl_down(bi, off);
      if (ov > bv || (ov == bv && oi < bi)) { bv = ov; bi = oi; }
    }
    if (lane == 0) { rv[wid] = bv; ri[wid] = bi; }
    __syncthreads();
    if (tid == 0) {
      float fv = rv[0]; int fi = ri[0];
      for (int w = 1; w < 4; ++w)
        if (rv[w] > fv || (rv[w] == fv && ri[w] < fi)) { fv = rv[w]; fi = ri[w]; }
      sval[round] = fv; sidx[round] = fi;
    }
    __syncthreads();
    int widx = sidx[round];
#pragma unroll
    for (int m = 0; m < 16; ++m)
      if (ix[m] == widx) v[m] = -1.f;
  }

  // exact fp32 refine: 8 threads per candidate
  {
    const int ci = tid >> 3, sub = tid & 7;
    const int lag = sidx[ci];
    float S = 0.f;
#pragma unroll 4
    for (int it = 0; it < 512; ++it) {
      int t = it * 8 + sub;
      S = fmaf(kf[t], qf[(t + lag) & (LQ - 1)], S);
    }
    S += __shfl_xor(S, 1);
    S += __shfl_xor(S, 2);
    S += __shfl_xor(S, 4);
    if (sub == 0) rS[ci] = S;
  }
  __syncthreads();

  if (tid < CAND) {
    float vi = fabsf(rS[tid]); int ii = sidx[tid];
    int rank = 0;
    for (int j = 0; j < CAND; ++j) {
      float vj = fabsf(rS[j]);
      rank += (vj > vi) || (vj == vi && sidx[j] < ii);
    }
    if (rank < TOPK) { ordv[rank] = vi; ordl[rank] = ii; }
  }
  __syncthreads();

  if (tid == 0) {
    float m0 = ordv[0], s = 0.f, e[TOPK];
    for (int k = 0; k < TOPK; ++k) { e[k] = expf(ordv[k] - m0); s += e[k]; }
    float inv = 1.f / s;
    int* ip = (int*)(lw + (size_t)row * 32);
    for (int k = 0; k < TOPK; ++k) {
      ip[k] = ordl[k];
      ((float*)ip)[TOPK + k] = e[k] * inv;
    }
  }
}

// ---------------------------------------------------------------------------
// Kernel 4: aggregation  aggT[row][t] = sum_k w_k * v[row][(t+lag_k)%L]
// ---------------------------------------------------------------------------
__global__ void agg_kernel(const float* __restrict__ vpT,
                           const float* __restrict__ lw,
                           float* __restrict__ aggT) {
  const int row = blockIdx.x, tid = threadIdx.x;
  __shared__ __align__(16) float vr[2 * LQ];
  __shared__ float w[TOPK]; __shared__ int lg[TOPK];

  const float* v0 = vpT + (size_t)row * LQ;
  for (int x = tid; x < LQ; x += 256) {
    float val = v0[x];
    vr[x] = val; vr[x + LQ] = val;
  }
  if (tid < TOPK) {
    lg[tid] = ((const int*)(lw + (size_t)row * 32))[tid];
    w[tid] = lw[(size_t)row * 32 + TOPK + tid];
  }
  __syncthreads();

  float wr[TOPK]; int lr[TOPK];
#pragma unroll
  for (int k = 0; k < TOPK; ++k) { wr[k] = w[k]; lr[k] = lg[k]; }

  for (int m = 0; m < 16; ++m) {
    int t = m * 256 + tid;
    float a = 0.f;
#pragma unroll
    for (int k = 0; k < TOPK; ++k) a = fmaf(wr[k], vr[t + lr[k]], a);
    aggT[(size_t)row * LQ + t] = a;
  }
}

// ---------------------------------------------------------------------------
// Kernel 5: transpose + head-broadcast  out[b][t][c] = aggT[b][c&63][t]
// ---------------------------------------------------------------------------
__global__ void trans_kernel(const float* __restrict__ aggT,
                             float* __restrict__ out) {
  const int b = blockIdx.y;
  const int t0 = blockIdx.x * 64;
  const int tid = threadIdx.x;
  __shared__ float ts[64][65];

#pragma unroll
  for (int v = 0; v < 16; ++v) {
    int f = v * 256 + tid;
    int d = f >> 6, tt = f & 63;
    ts[d][tt] = aggT[((size_t)b * DK + d) * LQ + t0 + tt];
  }
  __syncthreads();

#pragma unroll
  for (int v = 0; v < 128; ++v) {
    int f = v * 256 + tid;
    int tt = f >> 9, c = f & 511;
    out[((size_t)b * LQ + t0 + tt) * (8 * DK) + c] = ts[c & 63][tt];
  }
}

// ---------------------------------------------------------------------------
// ws layout (floats), peak 6M = 24 MB:
//   [0,1M) qp   [1M,2M) kp   [2M,3M) vp
//   [3M,4M) corrS   [4M,+8K) lw   [5M,6M) aggT
// ---------------------------------------------------------------------------
extern "C" void kernel_launch(void* const* d_in, const int* in_sizes, int n_in,
                              void* d_out, int out_size, void* d_ws, size_t ws_size,
                              hipStream_t stream) {
  const float* q_in = (const float*)d_in[0];
  const float* k_in = (const float*)d_in[1];
  const float* v_in = (const float*)d_in[2];
  const float* Wq   = (const float*)d_in[3];
  const float* bq   = (const float*)d_in[4];
  float* out = (float*)d_out;
  float* ws  = (float*)d_ws;

  const size_t M = (size_t)NROWS * LQ;        // 1,048,576 floats
  float* qp    = ws;
  float* kp    = ws + M;
  float* vp    = ws + 2 * M;
  float* corrS = ws + 3 * M;
  float* lw    = ws + 4 * M;
  float* aggT  = ws + 5 * M;

  proj_kernel<<<dim3(128, 1, 3), 256, 0, stream>>>(q_in, k_in, v_in, Wq, bq, ws);
  corr_kernel<<<NROWS, 256, 0, stream>>>(qp, kp, corrS);
  topk_kernel<<<NROWS, 256, 0, stream>>>(corrS, qp, kp, lw);
  agg_kernel<<<NROWS, 256, 0, stream>>>(vp, lw, aggT);
  trans_kernel<<<dim3(LQ / 64, BQ), 256, 0, stream>>>(aggT, out);
}

// Round 8
// 106.145 us; speedup vs baseline: 3.1514x; 1.2370x over previous
//
#include <hip/hip_runtime.h>
#include <hip/hip_bf16.h>

#define BQ 4
#define LQ 4096
#define DM 512
#define DK 64
#define NROWS (BQ * DK)        // 256
#define TOPK 16
#define CAND 32

typedef __attribute__((ext_vector_type(4))) short short4v;
typedef __attribute__((ext_vector_type(8))) short short8v;
typedef __attribute__((ext_vector_type(16))) float f32x16;
typedef unsigned long long ull;

__device__ __forceinline__ unsigned short f2bf(float x) {
  unsigned u = __builtin_bit_cast(unsigned, x);
  return (unsigned short)((u + 0x7FFFu + ((u >> 16) & 1u)) >> 16);
}
__device__ __forceinline__ float bf2f(unsigned short h) {
  unsigned u = ((unsigned)h) << 16;
  return __builtin_bit_cast(float, u);
}

// ---------------------------------------------------------------------------
// Kernel 1 (r7-proven): projection via split-bf16 MFMA (hh, hl, lh).
// ---------------------------------------------------------------------------
__global__ __launch_bounds__(256) void proj_kernel(
    const float* __restrict__ q_in, const float* __restrict__ k_in,
    const float* __restrict__ v_in, const float* __restrict__ Wq,
    const float* __restrict__ bq, float* __restrict__ ws) {
  const float* x = blockIdx.z == 0 ? q_in : (blockIdx.z == 1 ? k_in : v_in);
  float* outp = ws + (size_t)blockIdx.z * (size_t)(NROWS * LQ);

  __shared__ __align__(16) short sm[27648];   // 55296 B
  short* xh = sm;            // [128][72]
  short* xl = sm + 9216;
  short* wh = sm + 18432;    // [64][72]
  short* wl = sm + 23040;

  const int tid = threadIdx.x;
  const int l = tid & 63, wv = tid >> 6;
  const int R0 = blockIdx.x * 128;

  const int srow = tid >> 1;
  const int sp0 = (tid & 1) * 8;
  const int wcol = tid & 63;
  const int wk0 = (tid >> 6) * 16;

  f32x16 acc[2];
#pragma unroll
  for (int nt = 0; nt < 2; ++nt)
#pragma unroll
    for (int i = 0; i < 16; ++i) acc[nt][i] = 0.f;

  float4 xr[8];
  float wr[16];
#pragma unroll
  for (int c = 0; c < 8; ++c)
    xr[c] = *reinterpret_cast<const float4*>(
        &x[(size_t)(R0 + srow) * DM + (sp0 + c) * 4]);
#pragma unroll
  for (int u = 0; u < 16; ++u)
    wr[u] = Wq[(size_t)(wk0 + u) * DK + wcol];

  const int arow = wv * 32 + (l & 31);
  const int qn = l >> 5;
  const int aswz = 2 * ((arow >> 3) & 3);
  const int bc0 = l & 31;
  const int bswz0 = 2 * (((0 + bc0) >> 3) & 3);
  const int bswz1 = 2 * (((32 + bc0) >> 3) & 3);

  for (int kc = 0; kc < DM; kc += 64) {
    __syncthreads();
#pragma unroll
    for (int c = 0; c < 8; ++c) {
      int f4 = sp0 + c;
      int qd = (f4 >> 1) ^ (2 * ((srow >> 3) & 3));
      int base = srow * 72 + qd * 8 + (f4 & 1) * 4;
      float vv[4] = {xr[c].x, xr[c].y, xr[c].z, xr[c].w};
      short4v hi, lo;
#pragma unroll
      for (int i = 0; i < 4; ++i) {
        unsigned short h = f2bf(vv[i]);
        hi[i] = (short)h;
        lo[i] = (short)f2bf(vv[i] - bf2f(h));
      }
      *reinterpret_cast<short4v*>(xh + base) = hi;
      *reinterpret_cast<short4v*>(xl + base) = lo;
    }
#pragma unroll
    for (int qq = 0; qq < 2; ++qq) {
      int qd = ((wk0 >> 3) + qq) ^ (2 * ((wcol >> 3) & 3));
      int base = wcol * 72 + qd * 8;
      short8v hi, lo;
#pragma unroll
      for (int i = 0; i < 8; ++i) {
        float vv = wr[qq * 8 + i];
        unsigned short h = f2bf(vv);
        hi[i] = (short)h;
        lo[i] = (short)f2bf(vv - bf2f(h));
      }
      *reinterpret_cast<short8v*>(wh + base) = hi;
      *reinterpret_cast<short8v*>(wl + base) = lo;
    }
    __syncthreads();
    if (kc + 64 < DM) {
#pragma unroll
      for (int c = 0; c < 8; ++c)
        xr[c] = *reinterpret_cast<const float4*>(
            &x[(size_t)(R0 + srow) * DM + kc + 64 + (sp0 + c) * 4]);
#pragma unroll
      for (int u = 0; u < 16; ++u)
        wr[u] = Wq[(size_t)(kc + 64 + wk0 + u) * DK + wcol];
    }
#pragma unroll
    for (int ks = 0; ks < 4; ++ks) {
      int qA = (2 * ks + qn) ^ aswz;
      short8v ah = *reinterpret_cast<const short8v*>(xh + arow * 72 + qA * 8);
      short8v al_ = *reinterpret_cast<const short8v*>(xl + arow * 72 + qA * 8);
      {
        int qB = (2 * ks + qn) ^ bswz0;
        short8v bh = *reinterpret_cast<const short8v*>(wh + bc0 * 72 + qB * 8);
        short8v bl_ = *reinterpret_cast<const short8v*>(wl + bc0 * 72 + qB * 8);
        asm volatile("v_mfma_f32_32x32x16_bf16 %0, %1, %2, %0"
                     : "+v"(acc[0]) : "v"(ah), "v"(bh));
        asm volatile("v_mfma_f32_32x32x16_bf16 %0, %1, %2, %0"
                     : "+v"(acc[0]) : "v"(ah), "v"(bl_));
        asm volatile("v_mfma_f32_32x32x16_bf16 %0, %1, %2, %0"
                     : "+v"(acc[0]) : "v"(al_), "v"(bh));
      }
      {
        int qB = (2 * ks + qn) ^ bswz1;
        short8v bh = *reinterpret_cast<const short8v*>(wh + (32 + bc0) * 72 + qB * 8);
        short8v bl_ = *reinterpret_cast<const short8v*>(wl + (32 + bc0) * 72 + qB * 8);
        asm volatile("v_mfma_f32_32x32x16_bf16 %0, %1, %2, %0"
                     : "+v"(acc[1]) : "v"(ah), "v"(bh));
        asm volatile("v_mfma_f32_32x32x16_bf16 %0, %1, %2, %0"
                     : "+v"(acc[1]) : "v"(ah), "v"(bl_));
        asm volatile("v_mfma_f32_32x32x16_bf16 %0, %1, %2, %0"
                     : "+v"(acc[1]) : "v"(al_), "v"(bh));
      }
    }
  }

  asm volatile("s_nop 7\n\ts_nop 7\n\ts_nop 7" ::: "memory");
  __syncthreads();
  float* ts = (float*)sm;   // 8 areas of [32][34] f32
  const int b = R0 >> 12, i0 = R0 & (LQ - 1);
  float bb[2] = {bq[l & 31], bq[32 + (l & 31)]};
#pragma unroll
  for (int nt = 0; nt < 2; ++nt) {
    float* area = ts + (wv * 2 + nt) * 1088;
#pragma unroll
    for (int r = 0; r < 16; ++r) {
      int io = (r & 3) + 8 * (r >> 2) + 4 * (l >> 5);
      area[(l & 31) * 34 + io] = acc[nt][r] + bb[nt];
    }
  }
  __syncthreads();
  const int e = l & 15, jg = l >> 4;
#pragma unroll
  for (int nt = 0; nt < 2; ++nt) {
    const float* area = ts + (wv * 2 + nt) * 1088;
#pragma unroll
    for (int p = 0; p < 8; ++p) {
      int jj = jg * 8 + p;
      float2 v = *reinterpret_cast<const float2*>(area + jj * 34 + e * 2);
      *reinterpret_cast<float2*>(
          &outp[((size_t)b * DK + nt * 32 + jj) * LQ + i0 + wv * 32 + e * 2]) = v;
    }
  }
}

// ---------------------------------------------------------------------------
// Kernel 2 v7: FUSED corr + top-32 screen + exact refine + softmax.
// corr[tau] = sum_t k[t]*q[t+tau]  (MFMA Toeplitz, LDS-reduced, never to HBM)
// Screen: key=(|v|<<12)|(4095-tau); per-wave top-32 via barrier-free shfl
// butterflies; wave0 merges 128->32. Refine: exact fp32 (staged at entry).
// Output lw per row: [0..16) lag ints, [16..32) softmax weights.
// ---------------------------------------------------------------------------
__global__ __launch_bounds__(256) void corr_topk_kernel(
    const float* __restrict__ qp, const float* __restrict__ kp,
    float* __restrict__ lw) {
  const int row = blockIdx.x;
  const int tid = threadIdx.x;
  __shared__ __align__(16) short qs[3 * 4112 + 4096];  // 32864 B, red overlay
  __shared__ __align__(16) short ks[4096];
  __shared__ __align__(16) float qf[LQ];               // fp32 rows for refine
  __shared__ __align__(16) float kf[LQ];
  __shared__ __align__(16) ull wcand[4 * CAND];
  __shared__ int sidxL[CAND];
  __shared__ float rS[CAND];
  __shared__ float ordv[TOPK]; __shared__ int ordl[TOPK];

  const float* qr = qp + ((size_t)row << 12);
  const float* kr = kp + ((size_t)row << 12);

  // ---- staging: bf16 for MFMA + fp32 copies for refine ----
  {
    const float4* q4 = (const float4*)qr;
    float f[20];
#pragma unroll
    for (int c = 0; c < 4; ++c) {
      float4 v = q4[tid * 4 + c];
      ((float4*)qf)[tid * 4 + c] = v;
      f[c * 4 + 0] = v.x; f[c * 4 + 1] = v.y;
      f[c * 4 + 2] = v.z; f[c * 4 + 3] = v.w;
    }
    {
      float4 v = (tid == 255) ? q4[0] : q4[tid * 4 + 4];
      f[16] = v.x; f[17] = v.y; f[18] = v.z; f[19] = v.w;
    }
#pragma unroll
    for (int r = 0; r < 4; ++r) {
      short8v o0, o1;
#pragma unroll
      for (int i = 0; i < 8; ++i) {
        o0[i] = (short)f2bf(f[i + r]);
        o1[i] = (short)f2bf(f[8 + i + r]);
      }
      *(short8v*)(&qs[r * 4112 + tid * 16]) = o0;
      *(short8v*)(&qs[r * 4112 + tid * 16 + 8]) = o1;
    }
    const float4* k4 = (const float4*)kr;
    float g[16];
#pragma unroll
    for (int c = 0; c < 4; ++c) {
      float4 w = k4[tid * 4 + c];
      ((float4*)kf)[tid * 4 + c] = w;
      g[c * 4 + 0] = w.x; g[c * 4 + 1] = w.y;
      g[c * 4 + 2] = w.z; g[c * 4 + 3] = w.w;
    }
#pragma unroll
    for (int h = 0; h < 2; ++h) {
      int Q = 2 * tid + h;
      int Qs = Q ^ ((Q >> 3) & 7);
      short8v o;
#pragma unroll
      for (int i = 0; i < 8; ++i) o[i] = (short)f2bf(g[h * 8 + i]);
      *(short8v*)(&ks[Qs << 3]) = o;
    }
  }
  __syncthreads();

  const int l = tid & 63, wv = tid >> 6;
  const int Oq = ((8 * (l >> 5) - 32 * (l & 31)) & 4095) >> 3;
  const int rB = (l & 31) & 3;
  const int Ce = (l & 31) + 8 * (l >> 5) - rB;
  const short* qb = qs + rB * 4112;

  f32x16 acc[4];
#pragma unroll
  for (int M = 0; M < 4; ++M)
#pragma unroll
    for (int i = 0; i < 16; ++i) acc[M][i] = 0.f;

  const int J0 = wv * 64;
#pragma unroll 2
  for (int jb = 0; jb < 64; ++jb) {
    const int J = J0 + jb;
    int e1 = (Ce + 16 * J) & 4095;
    int e2 = (e1 + 4) & 4095;
    uint2 blo = *(const uint2*)(qb + e1);
    uint2 bhi = *(const uint2*)(qb + e2);
    int4 bi; bi.x = blo.x; bi.y = blo.y; bi.z = bhi.x; bi.w = bhi.y;
    short8v bf = __builtin_bit_cast(short8v, bi);
    const int Dq = 2 * J;
#pragma unroll
    for (int M = 0; M < 4; ++M) {
      int Q = (Oq + Dq - 128 * M) & 511;
      Q ^= (Q >> 3) & 7;
      short8v af = *(const short8v*)(&ks[Q << 3]);
      asm volatile("v_mfma_f32_32x32x16_bf16 %0, %1, %2, %0"
                   : "+v"(acc[M]) : "v"(af), "v"(bf));
    }
  }

  // ---- reduce 4 wave K-partials into red[0..4096) (overlay on qs) ----
  asm volatile("s_nop 7\n\ts_nop 7\n\ts_nop 7" ::: "memory");
  __syncthreads();
  float* red = (float*)qs;
  const int strip = (wv & 1) * 4096;
  const int ch4 = (l >> 5) * 4, cn = l & 31;
  if (wv < 2) {
#pragma unroll
    for (int M = 0; M < 4; ++M)
#pragma unroll
      for (int r = 0; r < 16; ++r)
        red[strip + (M << 10) + 32 * ((r & 3) + 8 * (r >> 2) + ch4) + cn] =
            acc[M][r];
  }
  __syncthreads();
  if (wv >= 2) {
#pragma unroll
    for (int M = 0; M < 4; ++M)
#pragma unroll
      for (int r = 0; r < 16; ++r)
        red[strip + (M << 10) + 32 * ((r & 3) + 8 * (r >> 2) + ch4) + cn] +=
            acc[M][r];
  }
  __syncthreads();
#pragma unroll
  for (int c = 0; c < 4; ++c) {
    int i = tid * 16 + c * 4;
    float4 a = *(const float4*)(&red[i]);
    float4 b2 = *(const float4*)(&red[4096 + i]);
    float4 o;
    o.x = a.x + b2.x; o.y = a.y + b2.y; o.z = a.z + b2.z; o.w = a.w + b2.w;
    *(float4*)(&red[i]) = o;
  }
  __syncthreads();

  // ---- screen: per-wave top-32, barrier-free shfl butterflies ----
  {
    ull key[16];
#pragma unroll
    for (int i = 0; i < 16; ++i) {
      int tau = wv * 1024 + i * 64 + l;
      unsigned u = __builtin_bit_cast(unsigned, fabsf(red[tau]));
      key[i] = ((ull)u << 12) | (unsigned)(4095 - tau);
    }
    ull bkey = key[0]; int bslot = 0;
#pragma unroll
    for (int i = 1; i < 16; ++i)
      if (key[i] > bkey) { bkey = key[i]; bslot = i; }
    for (int round = 0; round < CAND; ++round) {
      ull m = bkey;
#pragma unroll
      for (int off = 1; off < 64; off <<= 1) {
        ull o = __shfl_xor(m, off);
        m = o > m ? o : m;
      }
      if (l == 0) wcand[wv * CAND + round] = m;
      if (m == bkey) {
        key[bslot] = 0;
        bkey = key[0]; bslot = 0;
#pragma unroll
        for (int i = 1; i < 16; ++i)
          if (key[i] > bkey) { bkey = key[i]; bslot = i; }
      }
    }
  }
  __syncthreads();

  // ---- merge 128 -> top-32 (wave 0 only) ----
  if (wv == 0) {
    ull k0 = wcand[l], k1 = wcand[64 + l];
    for (int round = 0; round < CAND; ++round) {
      ull m = k0 > k1 ? k0 : k1;
#pragma unroll
      for (int off = 1; off < 64; off <<= 1) {
        ull o = __shfl_xor(m, off);
        m = o > m ? o : m;
      }
      if (l == 0) sidxL[round] = 4095 - (int)(m & 0xFFFu);
      if (m == k0) k0 = 0;
      else if (m == k1) k1 = 0;
    }
  }
  __syncthreads();

  // ---- exact fp32 refine: 8 threads/candidate, 4-way ILP ----
  {
    const int ci = tid >> 3, sub = tid & 7;
    const int lag = sidxL[ci];
    float S0 = 0.f, S1 = 0.f, S2 = 0.f, S3 = 0.f;
    for (int it = 0; it < 512; it += 4) {
      S0 = fmaf(kf[(it + 0) * 8 + sub], qf[((it + 0) * 8 + sub + lag) & 4095], S0);
      S1 = fmaf(kf[(it + 1) * 8 + sub], qf[((it + 1) * 8 + sub + lag) & 4095], S1);
      S2 = fmaf(kf[(it + 2) * 8 + sub], qf[((it + 2) * 8 + sub + lag) & 4095], S2);
      S3 = fmaf(kf[(it + 3) * 8 + sub], qf[((it + 3) * 8 + sub + lag) & 4095], S3);
    }
    float S = (S0 + S1) + (S2 + S3);
    S += __shfl_xor(S, 1);
    S += __shfl_xor(S, 2);
    S += __shfl_xor(S, 4);
    if (sub == 0) rS[ci] = S;
  }
  __syncthreads();

  // ---- rank 32 refined values (|S| desc, idx asc), top-16 + softmax ----
  if (tid < CAND) {
    float vi = fabsf(rS[tid]); int ii = sidxL[tid];
    int rank = 0;
    for (int j = 0; j < CAND; ++j) {
      float vj = fabsf(rS[j]);
      rank += (vj > vi) || (vj == vi && sidxL[j] < ii);
    }
    if (rank < TOPK) { ordv[rank] = vi; ordl[rank] = ii; }
  }
  __syncthreads();

  if (tid == 0) {
    float m0 = ordv[0], s = 0.f, e[TOPK];
    for (int k = 0; k < TOPK; ++k) { e[k] = expf(ordv[k] - m0); s += e[k]; }
    float inv = 1.f / s;
    int* ip = (int*)(lw + (size_t)row * 32);
    for (int k = 0; k < TOPK; ++k) {
      ip[k] = ordl[k];
      ((float*)ip)[TOPK + k] = e[k] * inv;
    }
  }
}

// ---------------------------------------------------------------------------
// Kernel 4: aggregation  aggT[row][t] = sum_k w_k * v[row][(t+lag_k)%L]
// ---------------------------------------------------------------------------
__global__ void agg_kernel(const float* __restrict__ vpT,
                           const float* __restrict__ lw,
                           float* __restrict__ aggT) {
  const int row = blockIdx.x, tid = threadIdx.x;
  __shared__ __align__(16) float vr[2 * LQ];
  __shared__ float w[TOPK]; __shared__ int lg[TOPK];

  const float* v0 = vpT + (size_t)row * LQ;
  for (int x = tid; x < LQ; x += 256) {
    float val = v0[x];
    vr[x] = val; vr[x + LQ] = val;
  }
  if (tid < TOPK) {
    lg[tid] = ((const int*)(lw + (size_t)row * 32))[tid];
    w[tid] = lw[(size_t)row * 32 + TOPK + tid];
  }
  __syncthreads();

  float wr[TOPK]; int lr[TOPK];
#pragma unroll
  for (int k = 0; k < TOPK; ++k) { wr[k] = w[k]; lr[k] = lg[k]; }

  for (int m = 0; m < 16; ++m) {
    int t = m * 256 + tid;
    float a = 0.f;
#pragma unroll
    for (int k = 0; k < TOPK; ++k) a = fmaf(wr[k], vr[t + lr[k]], a);
    aggT[(size_t)row * LQ + t] = a;
  }
}

// ---------------------------------------------------------------------------
// Kernel 5: transpose + head-broadcast  out[b][t][c] = aggT[b][c&63][t]
// ---------------------------------------------------------------------------
__global__ void trans_kernel(const float* __restrict__ aggT,
                             float* __restrict__ out) {
  const int b = blockIdx.y;
  const int t0 = blockIdx.x * 64;
  const int tid = threadIdx.x;
  __shared__ float ts[64][65];

#pragma unroll
  for (int v = 0; v < 16; ++v) {
    int f = v * 256 + tid;
    int d = f >> 6, tt = f & 63;
    ts[d][tt] = aggT[((size_t)b * DK + d) * LQ + t0 + tt];
  }
  __syncthreads();

#pragma unroll
  for (int v = 0; v < 128; ++v) {
    int f = v * 256 + tid;
    int tt = f >> 9, c = f & 511;
    out[((size_t)b * LQ + t0 + tt) * (8 * DK) + c] = ts[c & 63][tt];
  }
}

// ---------------------------------------------------------------------------
// ws layout (floats): [0,1M) qp  [1M,2M) kp  [2M,3M) vp
//                     [3M,+8K) lw  [4M,5M) aggT
// ---------------------------------------------------------------------------
extern "C" void kernel_launch(void* const* d_in, const int* in_sizes, int n_in,
                              void* d_out, int out_size, void* d_ws, size_t ws_size,
                              hipStream_t stream) {
  const float* q_in = (const float*)d_in[0];
  const float* k_in = (const float*)d_in[1];
  const float* v_in = (const float*)d_in[2];
  const float* Wq   = (const float*)d_in[3];
  const float* bq   = (const float*)d_in[4];
  float* out = (float*)d_out;
  float* ws  = (float*)d_ws;

  const size_t M = (size_t)NROWS * LQ;        // 1,048,576 floats
  float* qp   = ws;
  float* kp   = ws + M;
  float* vp   = ws + 2 * M;
  float* lw   = ws + 3 * M;
  float* aggT = ws + 4 * M;

  proj_kernel<<<dim3(128, 1, 3), 256, 0, stream>>>(q_in, k_in, v_in, Wq, bq, ws);
  corr_topk_kernel<<<NROWS, 256, 0, stream>>>(qp, kp, lw);
  agg_kernel<<<NROWS, 256, 0, stream>>>(vp, lw, aggT);
  trans_kernel<<<dim3(LQ / 64, BQ), 256, 0, stream>>>(aggT, out);
}

// Round 9
// 76.480 us; speedup vs baseline: 4.3737x; 1.3879x over previous
//
#include <hip/hip_runtime.h>
#include <hip/hip_bf16.h>

#define BQ 4
#define LQ 4096
#define DM 512
#define DK 64
#define NROWS (BQ * DK)        // 256
#define TOPK 16
#define CAND 32

typedef __attribute__((ext_vector_type(4))) short short4v;
typedef __attribute__((ext_vector_type(8))) short short8v;
typedef __attribute__((ext_vector_type(16))) float f32x16;

__device__ __forceinline__ unsigned short f2bf(float x) {
  unsigned u = __builtin_bit_cast(unsigned, x);
  return (unsigned short)((u + 0x7FFFu + ((u >> 16) & 1u)) >> 16);
}
__device__ __forceinline__ float bf2f(unsigned short h) {
  unsigned u = ((unsigned)h) << 16;
  return __builtin_bit_cast(float, u);
}

// ---------------------------------------------------------------------------
// Kernel 1 (r7-proven): projection via split-bf16 MFMA (hh, hl, lh).
// ---------------------------------------------------------------------------
__global__ __launch_bounds__(256) void proj_kernel(
    const float* __restrict__ q_in, const float* __restrict__ k_in,
    const float* __restrict__ v_in, const float* __restrict__ Wq,
    const float* __restrict__ bq, float* __restrict__ ws) {
  const float* x = blockIdx.z == 0 ? q_in : (blockIdx.z == 1 ? k_in : v_in);
  float* outp = ws + (size_t)blockIdx.z * (size_t)(NROWS * LQ);

  __shared__ __align__(16) short sm[27648];   // 55296 B
  short* xh = sm;            // [128][72]
  short* xl = sm + 9216;
  short* wh = sm + 18432;    // [64][72]
  short* wl = sm + 23040;

  const int tid = threadIdx.x;
  const int l = tid & 63, wv = tid >> 6;
  const int R0 = blockIdx.x * 128;

  const int srow = tid >> 1;
  const int sp0 = (tid & 1) * 8;
  const int wcol = tid & 63;
  const int wk0 = (tid >> 6) * 16;

  f32x16 acc[2];
#pragma unroll
  for (int nt = 0; nt < 2; ++nt)
#pragma unroll
    for (int i = 0; i < 16; ++i) acc[nt][i] = 0.f;

  float4 xr[8];
  float wr[16];
#pragma unroll
  for (int c = 0; c < 8; ++c)
    xr[c] = *reinterpret_cast<const float4*>(
        &x[(size_t)(R0 + srow) * DM + (sp0 + c) * 4]);
#pragma unroll
  for (int u = 0; u < 16; ++u)
    wr[u] = Wq[(size_t)(wk0 + u) * DK + wcol];

  const int arow = wv * 32 + (l & 31);
  const int qn = l >> 5;
  const int aswz = 2 * ((arow >> 3) & 3);
  const int bc0 = l & 31;
  const int bswz0 = 2 * (((0 + bc0) >> 3) & 3);
  const int bswz1 = 2 * (((32 + bc0) >> 3) & 3);

  for (int kc = 0; kc < DM; kc += 64) {
    __syncthreads();
#pragma unroll
    for (int c = 0; c < 8; ++c) {
      int f4 = sp0 + c;
      int qd = (f4 >> 1) ^ (2 * ((srow >> 3) & 3));
      int base = srow * 72 + qd * 8 + (f4 & 1) * 4;
      float vv[4] = {xr[c].x, xr[c].y, xr[c].z, xr[c].w};
      short4v hi, lo;
#pragma unroll
      for (int i = 0; i < 4; ++i) {
        unsigned short h = f2bf(vv[i]);
        hi[i] = (short)h;
        lo[i] = (short)f2bf(vv[i] - bf2f(h));
      }
      *reinterpret_cast<short4v*>(xh + base) = hi;
      *reinterpret_cast<short4v*>(xl + base) = lo;
    }
#pragma unroll
    for (int qq = 0; qq < 2; ++qq) {
      int qd = ((wk0 >> 3) + qq) ^ (2 * ((wcol >> 3) & 3));
      int base = wcol * 72 + qd * 8;
      short8v hi, lo;
#pragma unroll
      for (int i = 0; i < 8; ++i) {
        float vv = wr[qq * 8 + i];
        unsigned short h = f2bf(vv);
        hi[i] = (short)h;
        lo[i] = (short)f2bf(vv - bf2f(h));
      }
      *reinterpret_cast<short8v*>(wh + base) = hi;
      *reinterpret_cast<short8v*>(wl + base) = lo;
    }
    __syncthreads();
    if (kc + 64 < DM) {
#pragma unroll
      for (int c = 0; c < 8; ++c)
        xr[c] = *reinterpret_cast<const float4*>(
            &x[(size_t)(R0 + srow) * DM + kc + 64 + (sp0 + c) * 4]);
#pragma unroll
      for (int u = 0; u < 16; ++u)
        wr[u] = Wq[(size_t)(kc + 64 + wk0 + u) * DK + wcol];
    }
#pragma unroll
    for (int ks = 0; ks < 4; ++ks) {
      int qA = (2 * ks + qn) ^ aswz;
      short8v ah = *reinterpret_cast<const short8v*>(xh + arow * 72 + qA * 8);
      short8v al_ = *reinterpret_cast<const short8v*>(xl + arow * 72 + qA * 8);
      {
        int qB = (2 * ks + qn) ^ bswz0;
        short8v bh = *reinterpret_cast<const short8v*>(wh + bc0 * 72 + qB * 8);
        short8v bl_ = *reinterpret_cast<const short8v*>(wl + bc0 * 72 + qB * 8);
        asm volatile("v_mfma_f32_32x32x16_bf16 %0, %1, %2, %0"
                     : "+v"(acc[0]) : "v"(ah), "v"(bh));
        asm volatile("v_mfma_f32_32x32x16_bf16 %0, %1, %2, %0"
                     : "+v"(acc[0]) : "v"(ah), "v"(bl_));
        asm volatile("v_mfma_f32_32x32x16_bf16 %0, %1, %2, %0"
                     : "+v"(acc[0]) : "v"(al_), "v"(bh));
      }
      {
        int qB = (2 * ks + qn) ^ bswz1;
        short8v bh = *reinterpret_cast<const short8v*>(wh + (32 + bc0) * 72 + qB * 8);
        short8v bl_ = *reinterpret_cast<const short8v*>(wl + (32 + bc0) * 72 + qB * 8);
        asm volatile("v_mfma_f32_32x32x16_bf16 %0, %1, %2, %0"
                     : "+v"(acc[1]) : "v"(ah), "v"(bh));
        asm volatile("v_mfma_f32_32x32x16_bf16 %0, %1, %2, %0"
                     : "+v"(acc[1]) : "v"(ah), "v"(bl_));
        asm volatile("v_mfma_f32_32x32x16_bf16 %0, %1, %2, %0"
                     : "+v"(acc[1]) : "v"(al_), "v"(bh));
      }
    }
  }

  asm volatile("s_nop 7\n\ts_nop 7\n\ts_nop 7" ::: "memory");
  __syncthreads();
  float* ts = (float*)sm;   // 8 areas of [32][34] f32
  const int b = R0 >> 12, i0 = R0 & (LQ - 1);
  float bb[2] = {bq[l & 31], bq[32 + (l & 31)]};
#pragma unroll
  for (int nt = 0; nt < 2; ++nt) {
    float* area = ts + (wv * 2 + nt) * 1088;
#pragma unroll
    for (int r = 0; r < 16; ++r) {
      int io = (r & 3) + 8 * (r >> 2) + 4 * (l >> 5);
      area[(l & 31) * 34 + io] = acc[nt][r] + bb[nt];
    }
  }
  __syncthreads();
  const int e = l & 15, jg = l >> 4;
#pragma unroll
  for (int nt = 0; nt < 2; ++nt) {
    const float* area = ts + (wv * 2 + nt) * 1088;
#pragma unroll
    for (int p = 0; p < 8; ++p) {
      int jj = jg * 8 + p;
      float2 v = *reinterpret_cast<const float2*>(area + jj * 34 + e * 2);
      *reinterpret_cast<float2*>(
          &outp[((size_t)b * DK + nt * 32 + jj) * LQ + i0 + wv * 32 + e * 2]) = v;
    }
  }
}

// ---------------------------------------------------------------------------
// Kernel 2 v8: fused corr+topk, 8 waves, scratch-free screen.
// MFMA Toeplitz (K split 8 ways) -> 2-strip staged LDS reduction (overlay on
// dead qs) -> per-wave top-16 (32-bit keys, static zero-on-match) -> rank the
// 128-union -> refine top-32 exactly in fp32 from LDS -> top-16 + softmax.
// ---------------------------------------------------------------------------
__global__ __launch_bounds__(512) void corr_topk_kernel(
    const float* __restrict__ qp, const float* __restrict__ kp,
    float* __restrict__ lw) {
  const int row = blockIdx.x;
  const int tid = threadIdx.x;
  __shared__ __align__(16) short qs[3 * 4112 + 4096];  // 32864 B; red overlay
  __shared__ __align__(16) short ks[4096];             // 8192 B
  __shared__ __align__(16) float qf[LQ];               // fp32 for refine
  __shared__ __align__(16) float kf[LQ];
  __shared__ unsigned wk[128];
  __shared__ unsigned scand[CAND];
  __shared__ float rS[CAND];
  __shared__ float ordv[TOPK]; __shared__ int ordl[TOPK];

  const float* qr = qp + ((size_t)row << 12);
  const float* kr = kp + ((size_t)row << 12);

  // ---- staging: 4 shifted bf16 q copies, swizzled bf16 k, fp32 q/k ----
  {
    const float4* q4 = (const float4*)qr;
    float4 v0 = q4[tid * 2], v1 = q4[tid * 2 + 1];
    float4 v2 = q4[(tid * 2 + 2) & 1023];
    ((float4*)qf)[tid * 2] = v0;
    ((float4*)qf)[tid * 2 + 1] = v1;
    float f[12] = {v0.x, v0.y, v0.z, v0.w, v1.x, v1.y, v1.z, v1.w,
                   v2.x, v2.y, v2.z, v2.w};
#pragma unroll
    for (int r = 0; r < 4; ++r) {
      short8v o;
#pragma unroll
      for (int i = 0; i < 8; ++i) o[i] = (short)f2bf(f[i + r]);
      *(short8v*)(&qs[r * 4112 + tid * 8]) = o;
    }
    const float4* k4 = (const float4*)kr;
    float4 w0 = k4[tid * 2], w1 = k4[tid * 2 + 1];
    ((float4*)kf)[tid * 2] = w0;
    ((float4*)kf)[tid * 2 + 1] = w1;
    float g[8] = {w0.x, w0.y, w0.z, w0.w, w1.x, w1.y, w1.z, w1.w};
    int Q = tid;
    int Qs = Q ^ ((Q >> 3) & 7);
    short8v o;
#pragma unroll
    for (int i = 0; i < 8; ++i) o[i] = (short)f2bf(g[i]);
    *(short8v*)(&ks[Qs << 3]) = o;
  }
  __syncthreads();

  const int l = tid & 63, wv = tid >> 6;    // 8 waves
  const int Oq = ((8 * (l >> 5) - 32 * (l & 31)) & 4095) >> 3;
  const int rB = (l & 31) & 3;
  const int Ce = (l & 31) + 8 * (l >> 5) - rB;
  const short* qb = qs + rB * 4112;

  f32x16 acc[4];
#pragma unroll
  for (int M = 0; M < 4; ++M)
#pragma unroll
    for (int i = 0; i < 16; ++i) acc[M][i] = 0.f;

  const int J0 = wv * 32;
#pragma unroll 2
  for (int jb = 0; jb < 32; ++jb) {
    const int J = J0 + jb;
    int e1 = (Ce + 16 * J) & 4095;
    int e2 = (e1 + 4) & 4095;
    uint2 blo = *(const uint2*)(qb + e1);
    uint2 bhi = *(const uint2*)(qb + e2);
    int4 bi; bi.x = blo.x; bi.y = blo.y; bi.z = bhi.x; bi.w = bhi.y;
    short8v bf = __builtin_bit_cast(short8v, bi);
    const int Dq = 2 * J;
#pragma unroll
    for (int M = 0; M < 4; ++M) {
      int Q = (Oq + Dq - 128 * M) & 511;
      Q ^= (Q >> 3) & 7;
      short8v af = *(const short8v*)(&ks[Q << 3]);
      asm volatile("v_mfma_f32_32x32x16_bf16 %0, %1, %2, %0"
                   : "+v"(acc[M]) : "v"(af), "v"(bf));
    }
  }

  // ---- 2-strip staged reduction of 8 K-partials (overlay on dead qs) ----
  asm volatile("s_nop 7\n\ts_nop 7\n\ts_nop 7" ::: "memory");
  __syncthreads();                       // all MFMA reads of qs done
  float* red = (float*)qs;               // 2 strips x 4096 f32
  const int strip = (wv & 1) * 4096;
  const int ch4 = (l >> 5) * 4, cn = l & 31;
#define RIDX(M, r) (strip + ((M) << 10) + 32 * (((r)&3) + 8 * ((r) >> 2) + ch4) + cn)
  if (wv < 2) {
#pragma unroll
    for (int M = 0; M < 4; ++M)
#pragma unroll
      for (int r = 0; r < 16; ++r) red[RIDX(M, r)] = acc[M][r];
  }
  __syncthreads();
  if (wv >= 2 && wv < 4) {
#pragma unroll
    for (int M = 0; M < 4; ++M)
#pragma unroll
      for (int r = 0; r < 16; ++r) red[RIDX(M, r)] += acc[M][r];
  }
  __syncthreads();
  if (wv >= 4 && wv < 6) {
#pragma unroll
    for (int M = 0; M < 4; ++M)
#pragma unroll
      for (int r = 0; r < 16; ++r) red[RIDX(M, r)] += acc[M][r];
  }
  __syncthreads();
  if (wv >= 6) {
#pragma unroll
    for (int M = 0; M < 4; ++M)
#pragma unroll
      for (int r = 0; r < 16; ++r) red[RIDX(M, r)] += acc[M][r];
  }
  __syncthreads();
#undef RIDX

  // ---- screen: per-wave top-16 over 512 taus, 32-bit keys, no scratch ----
  {
    unsigned key[8];
#pragma unroll
    for (int i = 0; i < 8; ++i) {
      int tau = wv * 512 + i * 64 + l;
      float v = red[tau] + red[4096 + tau];
      unsigned u = __builtin_bit_cast(unsigned, fabsf(v));
      key[i] = (u & 0xFFFFF000u) | (unsigned)(4095 - tau);
    }
    unsigned bkey = key[0];
#pragma unroll
    for (int i = 1; i < 8; ++i) bkey = key[i] > bkey ? key[i] : bkey;
    for (int round = 0; round < 16; ++round) {
      unsigned m = bkey;
#pragma unroll
      for (int off = 1; off < 64; off <<= 1) {
        unsigned o = __shfl_xor(m, off);
        m = o > m ? o : m;
      }
      if (l == 0) wk[wv * 16 + round] = m;
#pragma unroll
      for (int i = 0; i < 8; ++i) key[i] = (key[i] == m) ? 0u : key[i];
      bkey = key[0];
#pragma unroll
      for (int i = 1; i < 8; ++i) bkey = key[i] > bkey ? key[i] : bkey;
    }
  }
  __syncthreads();

  // ---- rank the 128-union, keep approx top-32 (keys distinct) ----
  if (tid < 128) {
    unsigned ki = wk[tid];
    int rank = 0;
    for (int j = 0; j < 128; ++j) rank += (wk[j] > ki);
    if (rank < CAND) scand[rank] = ki;
  }
  __syncthreads();

  // ---- exact fp32 refine: 16 lanes/candidate, interleaved t ----
  {
    const int ci = tid >> 4, sub = tid & 15;
    const int lag = 4095 - (int)(scand[ci] & 0xFFFu);
    float S0 = 0.f, S1 = 0.f, S2 = 0.f, S3 = 0.f;
    for (int it = 0; it < 256; it += 4) {
      int t0 = (it + 0) * 16 + sub, t1 = (it + 1) * 16 + sub;
      int t2 = (it + 2) * 16 + sub, t3 = (it + 3) * 16 + sub;
      S0 = fmaf(kf[t0], qf[(t0 + lag) & 4095], S0);
      S1 = fmaf(kf[t1], qf[(t1 + lag) & 4095], S1);
      S2 = fmaf(kf[t2], qf[(t2 + lag) & 4095], S2);
      S3 = fmaf(kf[t3], qf[(t3 + lag) & 4095], S3);
    }
    float S = (S0 + S1) + (S2 + S3);
    S += __shfl_xor(S, 1);
    S += __shfl_xor(S, 2);
    S += __shfl_xor(S, 4);
    S += __shfl_xor(S, 8);
    if (sub == 0) rS[ci] = S;
  }
  __syncthreads();

  // ---- rank 32 refined values (|S| desc, idx asc), top-16 + softmax ----
  if (tid < CAND) {
    float vi = fabsf(rS[tid]);
    int ii = 4095 - (int)(scand[tid] & 0xFFFu);
    int rank = 0;
    for (int j = 0; j < CAND; ++j) {
      float vj = fabsf(rS[j]);
      int ij = 4095 - (int)(scand[j] & 0xFFFu);
      rank += (vj > vi) || (vj == vi && ij < ii);
    }
    if (rank < TOPK) { ordv[rank] = vi; ordl[rank] = ii; }
  }
  __syncthreads();

  if (tid == 0) {
    float m0 = ordv[0], s = 0.f, e[TOPK];
    for (int k = 0; k < TOPK; ++k) { e[k] = expf(ordv[k] - m0); s += e[k]; }
    float inv = 1.f / s;
    int* ip = (int*)(lw + (size_t)row * 32);
    for (int k = 0; k < TOPK; ++k) {
      ip[k] = ordl[k];
      ((float*)ip)[TOPK + k] = e[k] * inv;
    }
  }
}

// ---------------------------------------------------------------------------
// Kernel 4: aggregation  aggT[row][t] = sum_k w_k * v[row][(t+lag_k)%L]
// ---------------------------------------------------------------------------
__global__ void agg_kernel(const float* __restrict__ vpT,
                           const float* __restrict__ lw,
                           float* __restrict__ aggT) {
  const int row = blockIdx.x, tid = threadIdx.x;
  __shared__ __align__(16) float vr[2 * LQ];
  __shared__ float w[TOPK]; __shared__ int lg[TOPK];

  const float* v0 = vpT + (size_t)row * LQ;
  for (int x = tid; x < LQ; x += 256) {
    float val = v0[x];
    vr[x] = val; vr[x + LQ] = val;
  }
  if (tid < TOPK) {
    lg[tid] = ((const int*)(lw + (size_t)row * 32))[tid];
    w[tid] = lw[(size_t)row * 32 + TOPK + tid];
  }
  __syncthreads();

  float wr[TOPK]; int lr[TOPK];
#pragma unroll
  for (int k = 0; k < TOPK; ++k) { wr[k] = w[k]; lr[k] = lg[k]; }

  for (int m = 0; m < 16; ++m) {
    int t = m * 256 + tid;
    float a = 0.f;
#pragma unroll
    for (int k = 0; k < TOPK; ++k) a = fmaf(wr[k], vr[t + lr[k]], a);
    aggT[(size_t)row * LQ + t] = a;
  }
}

// ---------------------------------------------------------------------------
// Kernel 5: transpose + head-broadcast  out[b][t][c] = aggT[b][c&63][t]
// ---------------------------------------------------------------------------
__global__ void trans_kernel(const float* __restrict__ aggT,
                             float* __restrict__ out) {
  const int b = blockIdx.y;
  const int t0 = blockIdx.x * 64;
  const int tid = threadIdx.x;
  __shared__ float ts[64][65];

#pragma unroll
  for (int v = 0; v < 16; ++v) {
    int f = v * 256 + tid;
    int d = f >> 6, tt = f & 63;
    ts[d][tt] = aggT[((size_t)b * DK + d) * LQ + t0 + tt];
  }
  __syncthreads();

#pragma unroll
  for (int v = 0; v < 128; ++v) {
    int f = v * 256 + tid;
    int tt = f >> 9, c = f & 511;
    out[((size_t)b * LQ + t0 + tt) * (8 * DK) + c] = ts[c & 63][tt];
  }
}

// ---------------------------------------------------------------------------
// ws layout (floats): [0,1M) qp  [1M,2M) kp  [2M,3M) vp
//                     [3M,+8K) lw  [4M,5M) aggT
// ---------------------------------------------------------------------------
extern "C" void kernel_launch(void* const* d_in, const int* in_sizes, int n_in,
                              void* d_out, int out_size, void* d_ws, size_t ws_size,
                              hipStream_t stream) {
  const float* q_in = (const float*)d_in[0];
  const float* k_in = (const float*)d_in[1];
  const float* v_in = (const float*)d_in[2];
  const float* Wq   = (const float*)d_in[3];
  const float* bq   = (const float*)d_in[4];
  float* out = (float*)d_out;
  float* ws  = (float*)d_ws;

  const size_t M = (size_t)NROWS * LQ;        // 1,048,576 floats
  float* qp   = ws;
  float* kp   = ws + M;
  float* vp   = ws + 2 * M;
  float* lw   = ws + 3 * M;
  float* aggT = ws + 4 * M;

  proj_kernel<<<dim3(128, 1, 3), 256, 0, stream>>>(q_in, k_in, v_in, Wq, bq, ws);
  corr_topk_kernel<<<NROWS, 512, 0, stream>>>(qp, kp, lw);
  agg_kernel<<<NROWS, 256, 0, stream>>>(vp, lw, aggT);
  trans_kernel<<<dim3(LQ / 64, BQ), 256, 0, stream>>>(aggT, out);
}